// Round 10
// baseline (290.455 us; speedup 1.0000x reference)
//
#include <hip/hip_runtime.h>
#include <hip/hip_bf16.h>

typedef unsigned short u16;
typedef unsigned int u32;
typedef __bf16 bf16x8 __attribute__((ext_vector_type(8)));
typedef float f32x4 __attribute__((ext_vector_type(4)));

#define SEQ 2048
#define NH 16
#define PD 64
#define DM 1024

#if __has_builtin(__builtin_amdgcn_exp2f)
#define EXP2(x) __builtin_amdgcn_exp2f(x)
#else
#define EXP2(x) __expf((x) * 0.6931471805599453f)
#endif

__device__ __forceinline__ float bf2f(u16 s) {
  u32 t = ((u32)s) << 16;
  float f;
  __builtin_memcpy(&f, &t, 4);
  return f;
}
__device__ __forceinline__ u16 f2bf(float f) {
  u32 x;
  __builtin_memcpy(&x, &f, 4);
  x = (x + 0x7fffu + ((x >> 16) & 1u)) >> 16;
  return (u16)x;
}
__device__ __forceinline__ u32 pack2(float a, float b) {
  __hip_bfloat162 h = __float22bfloat162_rn(float2{a, b});
  u32 r;
  __builtin_memcpy(&r, &h, 4);
  return r;
}
// async global -> LDS, 16B per lane. lds dest = wave-uniform base + lane*16B.
__device__ __forceinline__ void gld16(const u16* g, u16* l) {
  __builtin_amdgcn_global_load_lds(
      (const __attribute__((address_space(1))) unsigned int*)(g),
      (__attribute__((address_space(3))) unsigned int*)(l), 16, 0, 0);
}

// ---------------- fused preprocessing: detect + convert_x + sinusoid + transpose5 + params
// One launch replaces 5. Every block recomputes the dtype flag locally from Wq's
// first 8KB (L2-resident after the first block -> ~free); block 0 also publishes
// it to *flag for the fo GEMM. Block-range partition:
//   [0,4096)      convert x (4 elems/thread)
//   [4096,6144)   sinusoid pos-emb (4 elems/thread)
//   [6144,7424)   transpose+convert the five 1024^2 weights (64x64 tiles)
//   [7424,7452)   biases + u + v -> fp32 params
struct PrepArgs {
  const void* x;
  const void* w0; const void* w1; const void* w2; const void* w3; const void* w4;
  const void* p0; const void* p1; const void* p2; const void* p3; const void* p4;
  const void* p5; const void* p6;
};

__global__ __launch_bounds__(256) void prep_kernel(PrepArgs pa,
                                                   u16* __restrict__ xb,
                                                   u16* __restrict__ sinb,
                                                   u16* __restrict__ WT,
                                                   float* __restrict__ pf,
                                                   int* __restrict__ flag) {
  __shared__ int sz[256], sh[256];
  __shared__ u16 t[64][72];
  int tid = threadIdx.x;

  // local dtype detect (same signature test as the old detect_kernel)
  {
    const u16* probe = (const u16*)pa.w0;
    int zeros = 0, huge = 0;
    for (int j = 0; j < 16; ++j) {
      int i = tid * 16 + j;
      u16 v = probe[i];
      int e = (v >> 7) & 0xFF;
      if (((i & 1) == 0) && v == 0) zeros++;
      if (e >= 0x8C) huge++;
    }
    sz[tid] = zeros; sh[tid] = huge;
    __syncthreads();
    for (int s = 128; s > 0; s >>= 1) {
      if (tid < s) { sz[tid] += sz[tid + s]; sh[tid] += sh[tid + s]; }
      __syncthreads();
    }
  }
  int f = (sz[0] > 1024 || sh[0] > 200) ? 1 : 0;
  int id = blockIdx.x;
  if (id == 0 && tid == 0) *flag = f;

  if (id < 4096) {
    // convert x (4M elems) to bf16
    int i = (id * 256 + tid) * 4;
    if (f) {
      float4 fv = *(const float4*)((const float*)pa.x + i);
      u16 o[4] __attribute__((aligned(8))) = {f2bf(fv.x), f2bf(fv.y), f2bf(fv.z), f2bf(fv.w)};
      *(uint2*)(xb + i) = *(const uint2*)o;
    } else {
      *(uint2*)(xb + i) = *(const uint2*)((const u16*)pa.x + i);
    }
  } else if (id < 6144) {
    // sinusoid position embedding [SEQ, DM] (bf16), 4 elems/thread
    int base = ((id - 4096) * 256 + tid) * 4;
    u16 o[4] __attribute__((aligned(8)));
#pragma unroll
    for (int e = 0; e < 4; ++e) {
      int idx = base + e;
      int s = idx >> 10;
      int i = idx & 1023;
      int j = i & 511;
      float invf = __expf(-(float)j * (9.210340371976184f / 512.0f));
      float ang = (float)s * invf;
      float val = (i < 512) ? __sinf(ang) : __cosf(ang);
      o[e] = f2bf(val);
    }
    *(uint2*)(sinb + base) = *(const uint2*)o;
  } else if (id < 7424) {
    // transpose + convert the five 1024x1024 weights
    int tt = id - 6144;
    int z = tt >> 8;
    int rem = tt & 255;
    const void* src = (z == 0) ? pa.w0 : (z == 1) ? pa.w1 : (z == 2) ? pa.w2
                     : (z == 3) ? pa.w3 : pa.w4;
    u16* out = WT + (size_t)z * DM * DM;
    int r0 = (rem >> 4) * 64, c0 = (rem & 15) * 64;
    int tr = tid >> 2;
    int tc = (tid & 3) * 16;
    if (f) {
      const float* g = (const float*)src + (size_t)(r0 + tr) * DM + c0 + tc;
#pragma unroll
      for (int q = 0; q < 4; ++q) {
        float4 fv = *(const float4*)(g + q * 4);
        t[tr][tc + q * 4 + 0] = f2bf(fv.x);
        t[tr][tc + q * 4 + 1] = f2bf(fv.y);
        t[tr][tc + q * 4 + 2] = f2bf(fv.z);
        t[tr][tc + q * 4 + 3] = f2bf(fv.w);
      }
    } else {
      const uint4* g = (const uint4*)((const u16*)src + (size_t)(r0 + tr) * DM + c0 + tc);
      uint4 a = g[0], bb = g[1];
      *(uint4*)&t[tr][tc] = a;
      *(uint4*)&t[tr][tc + 8] = bb;
    }
    __syncthreads();
    u16 tmp[16] __attribute__((aligned(16)));
#pragma unroll
    for (int jj = 0; jj < 16; ++jj) tmp[jj] = t[tc + jj][tr];
    uint4* o = (uint4*)(out + (size_t)(c0 + tr) * DM + r0 + tc);
    o[0] = *(const uint4*)&tmp[0];
    o[1] = *(const uint4*)&tmp[8];
  } else {
    // biases + u + v -> fp32 params (7168 total)
    int idx = (id - 7424) * 256 + tid;
    int seg = idx >> 10, off = idx & 1023;
    const void* s = (seg == 0) ? pa.p0 : (seg == 1) ? pa.p1 : (seg == 2) ? pa.p2
                   : (seg == 3) ? pa.p3 : (seg == 4) ? pa.p4 : (seg == 5) ? pa.p5 : pa.p6;
    pf[idx] = f ? ((const float*)s)[off] : bf2f(((const u16*)s)[off]);
  }
}

// ---------------- bf16 GEMM: BK=64, global_load_lds staging, 2-barrier K-loop ---------
// BK 32->64: 8 gld16 per stage into 32KB LDS (still 4 blocks/CU), fragments
// loaded per k-half (register footprint unchanged), 32 MFMAs per barrier pair,
// HALF the barrier drains (the m97 structure's known stall). LDS layout: two
// 8KB k-half segments per operand, rows 0..127 contiguous at stride 32 within
// each segment; XOR swizzle applies within each 32-k half on both sides.
// vtrans: z==2 writes C transposed as Vt[(b*1024+col)*2048 + s].
struct GemmArgs {
  const u16* A;  const u16* A3;
  const u16* Bt0; const u16* Bt1; const u16* Bt2; const u16* Bt3;
  const float* b0; const float* b1; const float* b2; const float* b3;
  void* C0; void* C1; void* C2; void* C3;
  int N, K, M3;
  const int* flag; int outFp32; int vtrans;
};

__global__ __launch_bounds__(256, 4) void gemm_bt_kernel(GemmArgs p) {
  __shared__ u16 As[128 * 64];
  __shared__ u16 Bs[128 * 64];
  int z = blockIdx.z;
  if (z == 3 && (int)blockIdx.y * 128 >= p.M3) return;
  const u16* A = (z == 3) ? p.A3 : p.A;
  const u16* Bt = (z == 0) ? p.Bt0 : (z == 1) ? p.Bt1 : (z == 2) ? p.Bt2 : p.Bt3;
  const float* bias = (z == 0) ? p.b0 : (z == 1) ? p.b1 : (z == 2) ? p.b2 : p.b3;
  void* Cv = (z == 0) ? p.C0 : (z == 1) ? p.C1 : (z == 2) ? p.C2 : p.C3;
  int K = p.K, N = p.N;
  bool f32o = p.outFp32 && (*p.flag);
  bool vt = p.vtrans && (z == 2);

  int tid = threadIdx.x;
  int wave = tid >> 6, lane = tid & 63;
  int quad = lane >> 4, l16 = lane & 15;
  int m0 = blockIdx.y * 128, n0 = blockIdx.x * 128;
  int wm = (wave >> 1) * 64, wn = (wave & 1) * 64;

  int trow = tid >> 2;
  int tcol = ((tid & 3) ^ ((tid >> 3) & 3)) * 8;  // pre-swizzled source chunk (within 32-k half)
  const u16* ga = A + (size_t)(m0 + trow) * K + tcol;
  const u16* gb = Bt + (size_t)(n0 + trow) * K + tcol;
  u16* lwa = As + wave * 512;
  u16* lwb = Bs + wave * 512;
  int slotx = (quad ^ ((l16 >> 1) & 3)) * 8;      // swizzled fragment chunk

  f32x4 acc[4][4] = {};

  for (int k0 = 0; k0 < K; k0 += 64) {
    __syncthreads();
    // k-half 0 (segments 0,1) and k-half 1 (segments 2,3) for A and B
    gld16(ga + k0, lwa);
    gld16(ga + (size_t)64 * K + k0, lwa + 2048);
    gld16(ga + k0 + 32, lwa + 4096);
    gld16(ga + (size_t)64 * K + k0 + 32, lwa + 6144);
    gld16(gb + k0, lwb);
    gld16(gb + (size_t)64 * K + k0, lwb + 2048);
    gld16(gb + k0 + 32, lwb + 4096);
    gld16(gb + (size_t)64 * K + k0 + 32, lwb + 6144);
    __syncthreads();
#pragma unroll
    for (int kh = 0; kh < 2; ++kh) {
      int kbase = kh * 4096;
      bf16x8 af[4], bfv[4];
#pragma unroll
      for (int i = 0; i < 4; ++i) {
        af[i] = *(const bf16x8*)&As[kbase + (wm + i * 16 + l16) * 32 + slotx];
        bfv[i] = *(const bf16x8*)&Bs[kbase + (wn + i * 16 + l16) * 32 + slotx];
      }
#pragma unroll
      for (int tm = 0; tm < 4; ++tm)
#pragma unroll
        for (int tn = 0; tn < 4; ++tn)
          acc[tm][tn] = __builtin_amdgcn_mfma_f32_16x16x32_bf16(af[tm], bfv[tn], acc[tm][tn], 0, 0, 0);
    }
  }

#pragma unroll
  for (int tm = 0; tm < 4; ++tm) {
    int row = m0 + wm + tm * 16 + quad * 4;
#pragma unroll
    for (int tn = 0; tn < 4; ++tn) {
      int col = n0 + wn + tn * 16 + l16;
      float bv = bias[col];
      if (vt) {
        // transposed V store: rows r are s-contiguous, same (b, col)
        u16 o4[4] __attribute__((aligned(8)));
#pragma unroll
        for (int r = 0; r < 4; ++r) o4[r] = f2bf(acc[tm][tn][r] + bv);
        int bq_ = row >> 11, s = row & 2047;
        *(uint2*)((u16*)Cv + ((size_t)(bq_ * 1024 + col)) * 2048 + s) = *(const uint2*)o4;
      } else {
#pragma unroll
        for (int r = 0; r < 4; ++r) {
          float val = acc[tm][tn][r] + bv;
          if (f32o) ((float*)Cv)[(size_t)(row + r) * N + col] = val;
          else ((u16*)Cv)[(size_t)(row + r) * N + col] = f2bf(val);
        }
      }
    }
  }
}

// ---------------- fused rel-attention v11: v9 + MFMA l-sum (gather stays inline) -------
// l[row] = P . ones via 2 extra MFMAs on the idle matrix pipe — output lands in
// EXACTLY oacc's C-layout (D col-independent for B==1), replacing rsum16 x4 +
// bf16 unpack (~60 VALU/iter); l is computed from the same bf16-rounded P the
// PV reads. Base v9: fixed-base softmax (no max/alpha — shift invariance +
// bounded inputs), single masked band, unpredicated gather, P stride 72,
// XOR-swizzled staging, log2e folded into the Q prescale.
__global__ __launch_bounds__(256, 4) void attn_kernel(
    const u16* __restrict__ Q, const u16* __restrict__ Kg,
    const u16* __restrict__ Vtg, const u16* __restrict__ Rg,
    const float* __restrict__ pf,
    u16* __restrict__ O) {
  __shared__ __align__(16) u16 KP[64 * 72];   // K blocked [2][64][32] / P [64][72]
  __shared__ __align__(16) u16 RVs[4096];     // R slice blocked / V blocked
  __shared__ __align__(16) u16 Bb[128 * 66];  // shared pos band (masked values)

  int tid = threadIdx.x, wave = tid >> 6, lane = tid & 63;
  int quad = lane >> 4, l16 = lane & 15;
  int id = blockIdx.x;
  int bh = (id & 7) + ((id >> 8) << 3);  // same-head blocks share id%8 -> same XCD
  int s0 = ((id >> 3) & 31) * 64;
  int b = bh >> 4, h = bh & 15;
  const float* pu = pf + 5 * 1024 + h * PD;
  const float* pv = pf + 6 * 1024 + h * PD;

  int arow = wave * 16 + l16;          // this lane's A-frag row
  int sl_base = wave * 16 + quad * 4;  // C-layout row base

  // staging geometry: 4 lanes cover one 64B line; wave covers 16 rows.
  // source chunk is XOR-swizzled so the (linear-dest) DMA lands a swizzled tile.
  int srow = wave * 16 + (lane >> 2);
  int scol = ((lane & 3) ^ ((lane >> 3) & 3)) * 8;
  u16* kbase = KP + wave * 512;
  u16* rvbase = RVs + wave * 512;
  int kb0 = l16 * 32 + (quad ^ ((l16 >> 1) & 3)) * 8;  // swizzled frag base

  // ---- prologue: Q fragments in registers, pre-scaled by (1/8)*log2(e) ----
  const float QS = 0.18033688011112042f;
  bf16x8 qu0, qu1, qv0a, qv1a, qv0b, qv1b;
  {
    const u16* qp = Q + ((size_t)(b * SEQ + s0 + arow)) * DM + h * PD;
    int row2 = s0 + arow + 1;
    if (row2 > SEQ - 1) row2 = SEQ - 1;  // clamped row feeds only never-read cells
    const u16* qp2 = Q + ((size_t)(b * SEQ + row2)) * DM + h * PD;
    u16 qa[16] __attribute__((aligned(16)));
    u16 qb[16] __attribute__((aligned(16)));
    *(uint4*)&qa[0] = *(const uint4*)(qp + quad * 8);
    *(uint4*)&qa[8] = *(const uint4*)(qp + 32 + quad * 8);
    *(uint4*)&qb[0] = *(const uint4*)(qp2 + quad * 8);
    *(uint4*)&qb[8] = *(const uint4*)(qp2 + 32 + quad * 8);
    u16 fu[16] __attribute__((aligned(16)));
    u16 fv0[16] __attribute__((aligned(16)));
    u16 fv1[16] __attribute__((aligned(16)));
#pragma unroll
    for (int j = 0; j < 8; ++j) {
      float u0 = pu[quad * 8 + j], u1 = pu[32 + quad * 8 + j];
      float v0 = pv[quad * 8 + j], v1 = pv[32 + quad * 8 + j];
      fu[j] = f2bf((bf2f(qa[j]) + u0) * QS);
      fu[8 + j] = f2bf((bf2f(qa[8 + j]) + u1) * QS);
      fv0[j] = f2bf((bf2f(qa[j]) + v0) * QS);
      fv0[8 + j] = f2bf((bf2f(qa[8 + j]) + v1) * QS);
      fv1[j] = f2bf((bf2f(qb[j]) + v0) * QS);
      fv1[8 + j] = f2bf((bf2f(qb[8 + j]) + v1) * QS);
    }
    __builtin_memcpy(&qu0, &fu[0], 16);
    __builtin_memcpy(&qu1, &fu[8], 16);
    __builtin_memcpy(&qv0a, &fv0[0], 16);
    __builtin_memcpy(&qv1a, &fv0[8], 16);
    __builtin_memcpy(&qv0b, &fv1[0], 16);
    __builtin_memcpy(&qv1b, &fv1[8], 16);
  }

  // all-ones B fragment (bf16 1.0 = 0x3F80) for the l = P . ones MFMA
  bf16x8 onesf;
  {
    u16 onearr[8] __attribute__((aligned(16)));
#pragma unroll
    for (int j = 0; j < 8; ++j) onearr[j] = 0x3F80;
    __builtin_memcpy(&onesf, onearr, 16);
  }

  // R-slice DMA with address clamp (OOB rows feed only masked-zero / never-read cells)
  auto dmaR = [&](int tb0) {
    int tg = tb0 + srow;
    tg = tg < 0 ? 0 : (tg > SEQ - 1 ? SEQ - 1 : tg);
    const u16* gr = Rg + (size_t)tg * DM + h * PD + scol;
    gld16(gr, rvbase);
    gld16(gr + 32, rvbase + 2048);
  };
  // one 64-row band slice: MFMA from RVs, store MASKED values (zero outside [lo,hi])
  // into band rows (slotBase + rloc + rowOff) & 127
  auto slice = [&](bf16x8 fa0, bf16x8 fa1, int slotBase, int rowOff, int lo, int hi) {
#pragma unroll
    for (int tt = 0; tt < 4; ++tt) {
      f32x4 pacc = {};
      bf16x8 b0 = *(const bf16x8*)&RVs[kb0 + tt * 512];
      bf16x8 b1 = *(const bf16x8*)&RVs[kb0 + tt * 512 + 2048];
      pacc = __builtin_amdgcn_mfma_f32_16x16x32_bf16(fa0, b0, pacc, 0, 0, 0);
      pacc = __builtin_amdgcn_mfma_f32_16x16x32_bf16(fa1, b1, pacc, 0, 0, 0);
      int rloc = tt * 16 + l16;
      bool ok = (rloc >= lo) & (rloc <= hi);
      u32 w0 = ok ? pack2(pacc[0], pacc[1]) : 0u;
      u32 w1 = ok ? pack2(pacc[2], pacc[3]) : 0u;
      int prow = (slotBase + rloc + rowOff) & 127;
      *(u32*)&Bb[prow * 66 + sl_base] = w0;
      *(u32*)&Bb[prow * 66 + sl_base + 2] = w1;
    }
  };

  f32x4 lacc = {};
  f32x4 oacc[4] = {};

  // ---- warmup: pass0 slice a=0 (rows U in [0,63], always valid) ----
  dmaR(SEQ - 65 - s0);
  __syncthreads();  // R landed
  slice(qv0a, qv1a, 0, 0, 0, 63);

  for (int j0 = 0; j0 < SEQ; j0 += 64) {
    int a1 = (j0 >> 6) + 1;
    int slot = (a1 & 1) << 6;
    bool p0n = (j0 <= s0);
    bool p1n = (j0 >= s0);
    __syncthreads();  // prev PV / warmup LDS reads done
    {
      const u16* gk = Kg + (size_t)(b * SEQ + j0 + srow) * DM + h * PD + scol;
      gld16(gk, kbase);
      gld16(gk + 32, kbase + 2048);
    }
    dmaR((p0n ? (SEQ - 65 - s0) : (-65 - s0)) + 64 * a1);
    __syncthreads();  // K + R landed

    // content scores -> C-layout registers
    f32x4 acc[4];
#pragma unroll
    for (int tn = 0; tn < 4; ++tn) {
      f32x4 a = {};
      bf16x8 b0 = *(const bf16x8*)&KP[kb0 + tn * 512];
      bf16x8 b1 = *(const bf16x8*)&KP[kb0 + tn * 512 + 2048];
      a = __builtin_amdgcn_mfma_f32_16x16x32_bf16(qu0, b0, a, 0, 0, 0);
      a = __builtin_amdgcn_mfma_f32_16x16x32_bf16(qu1, b1, a, 0, 0, 0);
      acc[tn] = a;
    }

    // new band slice(s), masked at the store:
    //   pass0: valid U = 64*a1+rloc <= s0+64  ->  rloc <= s0+64-64*a1
    //   pass1: valid U1 = 64*a1+rloc >= s0+65 ->  rloc >= s0+65-64*a1 (stored at +1)
    if (p0n) slice(qv0a, qv1a, slot, 0, 0, s0 + 64 - 64 * a1);
    if (p0n && p1n) {  // diagonal tile only: restage R for pass1 (also orders stores)
      __syncthreads();
      dmaR(64 * a1 - s0 - 65);
      __syncthreads();
    }
    if (p1n) slice(qv0b, qv1b, slot, 1, s0 + 65 - 64 * a1, 63);
    __syncthreads();  // band stores visible; RVs frag reads done

    // V DMA (drains at the pre-PV barrier, overlaps gather/softmax VALU)
    {
      const u16* gv = Vtg + ((size_t)(b * NH + h) * PD + srow) * SEQ + j0 + scol;
      gld16(gv, rvbase);
      gld16(gv + 32, rvbase + 2048);
    }

    // gather-add the shifted positional scores — unpredicated, single formula
    int g0 = l16 - sl_base + 64 + j0;
#pragma unroll
    for (int tn = 0; tn < 4; ++tn) {
#pragma unroll
      for (int r = 0; r < 4; ++r) {
        int rl = (g0 + tn * 16 - r) & 127;
        acc[tn][r] += bf2f(Bb[rl * 66 + sl_base + r]);
      }
    }

    // fixed-base softmax: P = exp2(S') directly (no max, no alpha — shift
    // invariance cancels the base in the final normalize); l via MFMA below
#pragma unroll
    for (int r = 0; r < 4; ++r) {
      u32 w0 = pack2(EXP2(acc[0][r]), EXP2(acc[1][r]));
      u32 w1 = pack2(EXP2(acc[2][r]), EXP2(acc[3][r]));
      u16 ec[4] = {(u16)w0, (u16)(w0 >> 16), (u16)w1, (u16)(w1 >> 16)};
      int row = sl_base + r;
      u16* prow_ = KP + row * 72 + l16;
#pragma unroll
      for (int cr = 0; cr < 4; ++cr) {
        int c = (cr + quad) & 3;  // quad-rotated column order: conflict-free banks
        prow_[c * 16] = ec[c];
      }
    }
    __syncthreads();  // V landed + P visible

    // PV — pure MFMA accumulate; l = P . ones rides the matrix pipe too
    {
      bf16x8 pa0 = *(const bf16x8*)&KP[arow * 72 + quad * 8];
      bf16x8 pa1 = *(const bf16x8*)&KP[arow * 72 + 32 + quad * 8];
      lacc = __builtin_amdgcn_mfma_f32_16x16x32_bf16(pa0, onesf, lacc, 0, 0, 0);
      lacc = __builtin_amdgcn_mfma_f32_16x16x32_bf16(pa1, onesf, lacc, 0, 0, 0);
#pragma unroll
      for (int tp = 0; tp < 4; ++tp) {
        bf16x8 b0 = *(const bf16x8*)&RVs[kb0 + tp * 512];
        bf16x8 b1 = *(const bf16x8*)&RVs[kb0 + tp * 512 + 2048];
        oacc[tp] = __builtin_amdgcn_mfma_f32_16x16x32_bf16(pa0, b0, oacc[tp], 0, 0, 0);
        oacc[tp] = __builtin_amdgcn_mfma_f32_16x16x32_bf16(pa1, b1, oacc[tp], 0, 0, 0);
      }
    }
  }

  // epilogue: lacc is already in oacc's C-layout (row = sl_base + r)
  float li[4];
#pragma unroll
  for (int r = 0; r < 4; ++r) li[r] = 1.f / lacc[r];
#pragma unroll
  for (int tp = 0; tp < 4; ++tp) {
    int pcol = tp * 16 + l16;
#pragma unroll
    for (int r = 0; r < 4; ++r) {
      int sg = s0 + sl_base + r;
      O[((size_t)(b * SEQ + sg)) * DM + h * PD + pcol] = f2bf(oacc[tp][r] * li[r]);
    }
  }
}

extern "C" void kernel_launch(void* const* d_in, const int* in_sizes, int n_in,
                              void* d_out, int out_size, void* d_ws, size_t ws_size,
                              hipStream_t stream) {
  (void)in_sizes; (void)n_in; (void)out_size; (void)ws_size;
  const void* x  = d_in[0];
  const void* Wq = d_in[1];
  const void* bq = d_in[2];
  const void* Wk = d_in[3];
  const void* bk = d_in[4];
  const void* Wv = d_in[5];
  const void* bv = d_in[6];
  const void* Wp = d_in[7];
  const void* bp = d_in[8];
  const void* Wo = d_in[9];
  const void* bo = d_in[10];
  const void* u  = d_in[11];
  const void* v  = d_in[12];

  char* base = (char*)d_ws;
  int* flag = (int*)base;
  float* pf = (float*)(base + 64);                       // 7168 floats
  u16* wbase = (u16*)(base + 64 + 7168 * 4);
  u16* WT   = wbase;                                     // 5M elems
  u16* xb   = WT + (size_t)5 * DM * DM;                  // 4M (aliased: attn out)
  u16* sinb = xb + (size_t)2 * SEQ * DM;                 // 2M
  u16* Qb   = sinb + (size_t)SEQ * DM;                   // 4M
  u16* Kb   = Qb + (size_t)2 * SEQ * DM;                 // 4M
  u16* Vtb  = Kb + (size_t)2 * SEQ * DM;                 // 4M (Vt direct from gemm)
  u16* Rb   = Vtb + (size_t)2 * SEQ * DM;                // 2M
  u16* Ab   = xb;   // x consumed by qkv gemm before attention writes here

  // one fused preprocessing launch (detect + convert_x + sinusoid + transpose5 + params)
  PrepArgs pa;
  pa.x = x;
  pa.w0 = Wq; pa.w1 = Wk; pa.w2 = Wv; pa.w3 = Wp; pa.w4 = Wo;
  pa.p0 = bq; pa.p1 = bk; pa.p2 = bv; pa.p3 = bp; pa.p4 = bo; pa.p5 = u; pa.p6 = v;
  prep_kernel<<<7452, 256, 0, stream>>>(pa, xb, sinb, WT, pf, flag);

  // fused QKV + positional-projection GEMM (z = 0..2: x @ {Wq,Wk,Wv}; z = 3: sin @ Wp)
  // z==2 writes V transposed directly into Vtb (vtrans).
  GemmArgs qkv;
  qkv.A = xb; qkv.A3 = sinb;
  qkv.Bt0 = WT; qkv.Bt1 = WT + (size_t)DM * DM; qkv.Bt2 = WT + (size_t)2 * DM * DM;
  qkv.Bt3 = WT + (size_t)3 * DM * DM;
  qkv.b0 = pf; qkv.b1 = pf + 1024; qkv.b2 = pf + 2048; qkv.b3 = pf + 3072;
  qkv.C0 = Qb; qkv.C1 = Kb; qkv.C2 = Vtb; qkv.C3 = Rb;
  qkv.N = DM; qkv.K = DM; qkv.M3 = SEQ; qkv.flag = flag; qkv.outFp32 = 0; qkv.vtrans = 1;
  gemm_bt_kernel<<<dim3(8, 32, 4), 256, 0, stream>>>(qkv);

  attn_kernel<<<dim3(1024), 256, 0, stream>>>(Qb, Kb, Vtb, Rb, pf, Ab);

  GemmArgs fo;
  fo.A = Ab; fo.A3 = Ab;
  fo.Bt0 = WT + (size_t)4 * DM * DM; fo.Bt1 = fo.Bt0; fo.Bt2 = fo.Bt0; fo.Bt3 = fo.Bt0;
  fo.b0 = pf + 4096; fo.b1 = fo.b0; fo.b2 = fo.b0; fo.b3 = fo.b0;
  fo.C0 = d_out; fo.C1 = d_out; fo.C2 = d_out; fo.C3 = d_out;
  fo.N = DM; fo.K = DM; fo.M3 = 0; fo.flag = flag; fo.outFp32 = 1; fo.vtrans = 0;
  gemm_bt_kernel<<<dim3(8, 32, 1), 256, 0, stream>>>(fo);
}

// Round 11
// 284.506 us; speedup vs baseline: 1.0209x; 1.0209x over previous
//
#include <hip/hip_runtime.h>
#include <hip/hip_bf16.h>

typedef unsigned short u16;
typedef unsigned int u32;
typedef __bf16 bf16x8 __attribute__((ext_vector_type(8)));
typedef float f32x4 __attribute__((ext_vector_type(4)));

#define SEQ 2048
#define NH 16
#define PD 64
#define DM 1024

#if __has_builtin(__builtin_amdgcn_exp2f)
#define EXP2(x) __builtin_amdgcn_exp2f(x)
#else
#define EXP2(x) __expf((x) * 0.6931471805599453f)
#endif

__device__ __forceinline__ float bf2f(u16 s) {
  u32 t = ((u32)s) << 16;
  float f;
  __builtin_memcpy(&f, &t, 4);
  return f;
}
__device__ __forceinline__ u16 f2bf(float f) {
  u32 x;
  __builtin_memcpy(&x, &f, 4);
  x = (x + 0x7fffu + ((x >> 16) & 1u)) >> 16;
  return (u16)x;
}
__device__ __forceinline__ u32 pack2(float a, float b) {
  __hip_bfloat162 h = __float22bfloat162_rn(float2{a, b});
  u32 r;
  __builtin_memcpy(&r, &h, 4);
  return r;
}
// async global -> LDS, 16B per lane. lds dest = wave-uniform base + lane*16B.
__device__ __forceinline__ void gld16(const u16* g, u16* l) {
  __builtin_amdgcn_global_load_lds(
      (const __attribute__((address_space(1))) unsigned int*)(g),
      (__attribute__((address_space(3))) unsigned int*)(l), 16, 0, 0);
}

// ---------------- fused preprocessing: detect + convert_x + sinusoid + transpose5 + params
struct PrepArgs {
  const void* x;
  const void* w0; const void* w1; const void* w2; const void* w3; const void* w4;
  const void* p0; const void* p1; const void* p2; const void* p3; const void* p4;
  const void* p5; const void* p6;
};

__global__ __launch_bounds__(256) void prep_kernel(PrepArgs pa,
                                                   u16* __restrict__ xb,
                                                   u16* __restrict__ sinb,
                                                   u16* __restrict__ WT,
                                                   float* __restrict__ pf,
                                                   int* __restrict__ flag) {
  __shared__ int sz[256], sh[256];
  __shared__ u16 t[64][72];
  int tid = threadIdx.x;

  // local dtype detect (same signature test as the old detect_kernel)
  {
    const u16* probe = (const u16*)pa.w0;
    int zeros = 0, huge = 0;
    for (int j = 0; j < 16; ++j) {
      int i = tid * 16 + j;
      u16 v = probe[i];
      int e = (v >> 7) & 0xFF;
      if (((i & 1) == 0) && v == 0) zeros++;
      if (e >= 0x8C) huge++;
    }
    sz[tid] = zeros; sh[tid] = huge;
    __syncthreads();
    for (int s = 128; s > 0; s >>= 1) {
      if (tid < s) { sz[tid] += sz[tid + s]; sh[tid] += sh[tid + s]; }
      __syncthreads();
    }
  }
  int f = (sz[0] > 1024 || sh[0] > 200) ? 1 : 0;
  int id = blockIdx.x;
  if (id == 0 && tid == 0) *flag = f;

  if (id < 4096) {
    // convert x (4M elems) to bf16
    int i = (id * 256 + tid) * 4;
    if (f) {
      float4 fv = *(const float4*)((const float*)pa.x + i);
      u16 o[4] __attribute__((aligned(8))) = {f2bf(fv.x), f2bf(fv.y), f2bf(fv.z), f2bf(fv.w)};
      *(uint2*)(xb + i) = *(const uint2*)o;
    } else {
      *(uint2*)(xb + i) = *(const uint2*)((const u16*)pa.x + i);
    }
  } else if (id < 6144) {
    // sinusoid position embedding [SEQ, DM] (bf16), 4 elems/thread
    int base = ((id - 4096) * 256 + tid) * 4;
    u16 o[4] __attribute__((aligned(8)));
#pragma unroll
    for (int e = 0; e < 4; ++e) {
      int idx = base + e;
      int s = idx >> 10;
      int i = idx & 1023;
      int j = i & 511;
      float invf = __expf(-(float)j * (9.210340371976184f / 512.0f));
      float ang = (float)s * invf;
      float val = (i < 512) ? __sinf(ang) : __cosf(ang);
      o[e] = f2bf(val);
    }
    *(uint2*)(sinb + base) = *(const uint2*)o;
  } else if (id < 7424) {
    // transpose + convert the five 1024x1024 weights
    int tt = id - 6144;
    int z = tt >> 8;
    int rem = tt & 255;
    const void* src = (z == 0) ? pa.w0 : (z == 1) ? pa.w1 : (z == 2) ? pa.w2
                     : (z == 3) ? pa.w3 : pa.w4;
    u16* out = WT + (size_t)z * DM * DM;
    int r0 = (rem >> 4) * 64, c0 = (rem & 15) * 64;
    int tr = tid >> 2;
    int tc = (tid & 3) * 16;
    if (f) {
      const float* g = (const float*)src + (size_t)(r0 + tr) * DM + c0 + tc;
#pragma unroll
      for (int q = 0; q < 4; ++q) {
        float4 fv = *(const float4*)(g + q * 4);
        t[tr][tc + q * 4 + 0] = f2bf(fv.x);
        t[tr][tc + q * 4 + 1] = f2bf(fv.y);
        t[tr][tc + q * 4 + 2] = f2bf(fv.z);
        t[tr][tc + q * 4 + 3] = f2bf(fv.w);
      }
    } else {
      const uint4* g = (const uint4*)((const u16*)src + (size_t)(r0 + tr) * DM + c0 + tc);
      uint4 a = g[0], bb = g[1];
      *(uint4*)&t[tr][tc] = a;
      *(uint4*)&t[tr][tc + 8] = bb;
    }
    __syncthreads();
    u16 tmp[16] __attribute__((aligned(16)));
#pragma unroll
    for (int jj = 0; jj < 16; ++jj) tmp[jj] = t[tc + jj][tr];
    uint4* o = (uint4*)(out + (size_t)(c0 + tr) * DM + r0 + tc);
    o[0] = *(const uint4*)&tmp[0];
    o[1] = *(const uint4*)&tmp[8];
  } else {
    // biases + u + v -> fp32 params (7168 total)
    int idx = (id - 7424) * 256 + tid;
    int seg = idx >> 10, off = idx & 1023;
    const void* s = (seg == 0) ? pa.p0 : (seg == 1) ? pa.p1 : (seg == 2) ? pa.p2
                   : (seg == 3) ? pa.p3 : (seg == 4) ? pa.p4 : (seg == 5) ? pa.p5 : pa.p6;
    pf[idx] = f ? ((const float*)s)[off] : bf2f(((const u16*)s)[off]);
  }
}

// ---------------- merged QKV(+R) GEMM: shared-A staging, 128x64 tiles ----------------
// The three QKV GEMMs share A (=x): stage A ONCE per K-step (2 gld16) + three
// 64x32 B panels (1 gld16 each) -> 5 gld16 per 96 block-MFMAs vs 12 before
// (2.4x MFMA-per-staged-byte), one barrier pair instead of three. R (sin@Wp)
// rides as m-tiles 32..47 (block-uniform branch, fully unrolled — no runtime-z
// acc indexing, no scratch). z==2 output stored transposed as Vt (proven
// formula). All staging/frag/swizzle/epilogue formulas verbatim from gemm_bt.
__global__ __launch_bounds__(256, 3) void qkv_kernel(
    const u16* __restrict__ xb, const u16* __restrict__ sinb,
    const u16* __restrict__ WT, const float* __restrict__ pf,
    u16* __restrict__ Qb, u16* __restrict__ Kb, u16* __restrict__ Vtb,
    u16* __restrict__ Rb) {
  __shared__ u16 As[128 * 32];      // 8KB
  __shared__ u16 Bs[3 * 64 * 32];   // 12KB (panels z*2048)
  int tid = threadIdx.x;
  int wave = tid >> 6, lane = tid & 63;
  int quad = lane >> 4, l16 = lane & 15;
  int bx = blockIdx.x, by = blockIdx.y;
  bool isR = by >= 32;
  int m0 = (isR ? (by - 32) : by) * 128;
  int n0 = bx * 64;
  int wm = (wave >> 1) * 64, wn = (wave & 1) * 32;

  int trow = tid >> 2;
  int tcol = ((tid & 3) ^ ((tid >> 3) & 3)) * 8;  // pre-swizzled source chunk
  const u16* A = isR ? sinb : xb;
  const u16* ga = A + (size_t)(m0 + trow) * DM + tcol;
  const u16* gb = WT + (isR ? (size_t)3 * DM * DM : 0) + (size_t)(n0 + trow) * DM + tcol;
  u16* lwa = As + wave * 512;
  u16* lwb = Bs + wave * 512;
  int slotx = (quad ^ ((l16 >> 1) & 3)) * 8;      // swizzled fragment chunk

  if (!isR) {
    f32x4 acc[3][4][2] = {};
    for (int k0 = 0; k0 < DM; k0 += 32) {
      __syncthreads();
      gld16(ga + k0, lwa);
      gld16(ga + (size_t)64 * DM + k0, lwa + 2048);
      gld16(gb + k0, lwb);
      gld16(gb + (size_t)DM * DM + k0, lwb + 2048);
      gld16(gb + (size_t)2 * DM * DM + k0, lwb + 4096);
      __syncthreads();
      bf16x8 af[4];
#pragma unroll
      for (int i = 0; i < 4; ++i)
        af[i] = *(const bf16x8*)&As[(wm + i * 16 + l16) * 32 + slotx];
#pragma unroll
      for (int z = 0; z < 3; ++z) {
        bf16x8 b0 = *(const bf16x8*)&Bs[z * 2048 + (wn + l16) * 32 + slotx];
        bf16x8 b1 = *(const bf16x8*)&Bs[z * 2048 + (wn + 16 + l16) * 32 + slotx];
#pragma unroll
        for (int tm = 0; tm < 4; ++tm) {
          acc[z][tm][0] = __builtin_amdgcn_mfma_f32_16x16x32_bf16(af[tm], b0, acc[z][tm][0], 0, 0, 0);
          acc[z][tm][1] = __builtin_amdgcn_mfma_f32_16x16x32_bf16(af[tm], b1, acc[z][tm][1], 0, 0, 0);
        }
      }
    }
    // epilogue: Q, K normal; V transposed (proven vtrans formula)
#pragma unroll
    for (int tm = 0; tm < 4; ++tm) {
      int row = m0 + wm + tm * 16 + quad * 4;
#pragma unroll
      for (int tn = 0; tn < 2; ++tn) {
        int col = n0 + wn + tn * 16 + l16;
        float bq = pf[col], bk = pf[1024 + col], bv = pf[2048 + col];
#pragma unroll
        for (int r = 0; r < 4; ++r) {
          Qb[(size_t)(row + r) * DM + col] = f2bf(acc[0][tm][tn][r] + bq);
          Kb[(size_t)(row + r) * DM + col] = f2bf(acc[1][tm][tn][r] + bk);
        }
        u16 o4[4] __attribute__((aligned(8)));
#pragma unroll
        for (int r = 0; r < 4; ++r) o4[r] = f2bf(acc[2][tm][tn][r] + bv);
        int bq_ = row >> 11, s = row & 2047;
        *(uint2*)(Vtb + ((size_t)(bq_ * 1024 + col)) * 2048 + s) = *(const uint2*)o4;
      }
    }
  } else {
    f32x4 acc[4][2] = {};
    for (int k0 = 0; k0 < DM; k0 += 32) {
      __syncthreads();
      gld16(ga + k0, lwa);
      gld16(ga + (size_t)64 * DM + k0, lwa + 2048);
      gld16(gb + k0, lwb);
      __syncthreads();
      bf16x8 af[4];
#pragma unroll
      for (int i = 0; i < 4; ++i)
        af[i] = *(const bf16x8*)&As[(wm + i * 16 + l16) * 32 + slotx];
      bf16x8 b0 = *(const bf16x8*)&Bs[(wn + l16) * 32 + slotx];
      bf16x8 b1 = *(const bf16x8*)&Bs[(wn + 16 + l16) * 32 + slotx];
#pragma unroll
      for (int tm = 0; tm < 4; ++tm) {
        acc[tm][0] = __builtin_amdgcn_mfma_f32_16x16x32_bf16(af[tm], b0, acc[tm][0], 0, 0, 0);
        acc[tm][1] = __builtin_amdgcn_mfma_f32_16x16x32_bf16(af[tm], b1, acc[tm][1], 0, 0, 0);
      }
    }
#pragma unroll
    for (int tm = 0; tm < 4; ++tm) {
      int row = m0 + wm + tm * 16 + quad * 4;
#pragma unroll
      for (int tn = 0; tn < 2; ++tn) {
        int col = n0 + wn + tn * 16 + l16;
        float br = pf[3072 + col];
#pragma unroll
        for (int r = 0; r < 4; ++r)
          Rb[(size_t)(row + r) * DM + col] = f2bf(acc[tm][tn][r] + br);
      }
    }
  }
}

// ---------------- bf16 GEMM (fo only): BK=64, global_load_lds staging ----------------
struct GemmArgs {
  const u16* A;  const u16* A3;
  const u16* Bt0; const u16* Bt1; const u16* Bt2; const u16* Bt3;
  const float* b0; const float* b1; const float* b2; const float* b3;
  void* C0; void* C1; void* C2; void* C3;
  int N, K, M3;
  const int* flag; int outFp32; int vtrans;
};

__global__ __launch_bounds__(256, 4) void gemm_bt_kernel(GemmArgs p) {
  __shared__ u16 As[128 * 64];
  __shared__ u16 Bs[128 * 64];
  int z = blockIdx.z;
  if (z == 3 && (int)blockIdx.y * 128 >= p.M3) return;
  const u16* A = (z == 3) ? p.A3 : p.A;
  const u16* Bt = (z == 0) ? p.Bt0 : (z == 1) ? p.Bt1 : (z == 2) ? p.Bt2 : p.Bt3;
  const float* bias = (z == 0) ? p.b0 : (z == 1) ? p.b1 : (z == 2) ? p.b2 : p.b3;
  void* Cv = (z == 0) ? p.C0 : (z == 1) ? p.C1 : (z == 2) ? p.C2 : p.C3;
  int K = p.K, N = p.N;
  bool f32o = p.outFp32 && (*p.flag);
  bool vt = p.vtrans && (z == 2);

  int tid = threadIdx.x;
  int wave = tid >> 6, lane = tid & 63;
  int quad = lane >> 4, l16 = lane & 15;
  int m0 = blockIdx.y * 128, n0 = blockIdx.x * 128;
  int wm = (wave >> 1) * 64, wn = (wave & 1) * 64;

  int trow = tid >> 2;
  int tcol = ((tid & 3) ^ ((tid >> 3) & 3)) * 8;  // pre-swizzled source chunk (within 32-k half)
  const u16* ga = A + (size_t)(m0 + trow) * K + tcol;
  const u16* gb = Bt + (size_t)(n0 + trow) * K + tcol;
  u16* lwa = As + wave * 512;
  u16* lwb = Bs + wave * 512;
  int slotx = (quad ^ ((l16 >> 1) & 3)) * 8;      // swizzled fragment chunk

  f32x4 acc[4][4] = {};

  for (int k0 = 0; k0 < K; k0 += 64) {
    __syncthreads();
    gld16(ga + k0, lwa);
    gld16(ga + (size_t)64 * K + k0, lwa + 2048);
    gld16(ga + k0 + 32, lwa + 4096);
    gld16(ga + (size_t)64 * K + k0 + 32, lwa + 6144);
    gld16(gb + k0, lwb);
    gld16(gb + (size_t)64 * K + k0, lwb + 2048);
    gld16(gb + k0 + 32, lwb + 4096);
    gld16(gb + (size_t)64 * K + k0 + 32, lwb + 6144);
    __syncthreads();
#pragma unroll
    for (int kh = 0; kh < 2; ++kh) {
      int kbase = kh * 4096;
      bf16x8 af[4], bfv[4];
#pragma unroll
      for (int i = 0; i < 4; ++i) {
        af[i] = *(const bf16x8*)&As[kbase + (wm + i * 16 + l16) * 32 + slotx];
        bfv[i] = *(const bf16x8*)&Bs[kbase + (wn + i * 16 + l16) * 32 + slotx];
      }
#pragma unroll
      for (int tm = 0; tm < 4; ++tm)
#pragma unroll
        for (int tn = 0; tn < 4; ++tn)
          acc[tm][tn] = __builtin_amdgcn_mfma_f32_16x16x32_bf16(af[tm], bfv[tn], acc[tm][tn], 0, 0, 0);
    }
  }

#pragma unroll
  for (int tm = 0; tm < 4; ++tm) {
    int row = m0 + wm + tm * 16 + quad * 4;
#pragma unroll
    for (int tn = 0; tn < 4; ++tn) {
      int col = n0 + wn + tn * 16 + l16;
      float bv = bias[col];
      if (vt) {
        u16 o4[4] __attribute__((aligned(8)));
#pragma unroll
        for (int r = 0; r < 4; ++r) o4[r] = f2bf(acc[tm][tn][r] + bv);
        int bq_ = row >> 11, s = row & 2047;
        *(uint2*)((u16*)Cv + ((size_t)(bq_ * 1024 + col)) * 2048 + s) = *(const uint2*)o4;
      } else {
#pragma unroll
        for (int r = 0; r < 4; ++r) {
          float val = acc[tm][tn][r] + bv;
          if (f32o) ((float*)Cv)[(size_t)(row + r) * N + col] = val;
          else ((u16*)Cv)[(size_t)(row + r) * N + col] = f2bf(val);
        }
      }
    }
  }
}

// ---------------- fused rel-attention v11: fixed-base softmax + MFMA l-sum ----------
__global__ __launch_bounds__(256, 4) void attn_kernel(
    const u16* __restrict__ Q, const u16* __restrict__ Kg,
    const u16* __restrict__ Vtg, const u16* __restrict__ Rg,
    const float* __restrict__ pf,
    u16* __restrict__ O) {
  __shared__ __align__(16) u16 KP[64 * 72];   // K blocked [2][64][32] / P [64][72]
  __shared__ __align__(16) u16 RVs[4096];     // R slice blocked / V blocked
  __shared__ __align__(16) u16 Bb[128 * 66];  // shared pos band (masked values)

  int tid = threadIdx.x, wave = tid >> 6, lane = tid & 63;
  int quad = lane >> 4, l16 = lane & 15;
  int id = blockIdx.x;
  int bh = (id & 7) + ((id >> 8) << 3);  // same-head blocks share id%8 -> same XCD
  int s0 = ((id >> 3) & 31) * 64;
  int b = bh >> 4, h = bh & 15;
  const float* pu = pf + 5 * 1024 + h * PD;
  const float* pv = pf + 6 * 1024 + h * PD;

  int arow = wave * 16 + l16;          // this lane's A-frag row
  int sl_base = wave * 16 + quad * 4;  // C-layout row base

  int srow = wave * 16 + (lane >> 2);
  int scol = ((lane & 3) ^ ((lane >> 3) & 3)) * 8;
  u16* kbase = KP + wave * 512;
  u16* rvbase = RVs + wave * 512;
  int kb0 = l16 * 32 + (quad ^ ((l16 >> 1) & 3)) * 8;  // swizzled frag base

  // ---- prologue: Q fragments in registers, pre-scaled by (1/8)*log2(e) ----
  const float QS = 0.18033688011112042f;
  bf16x8 qu0, qu1, qv0a, qv1a, qv0b, qv1b;
  {
    const u16* qp = Q + ((size_t)(b * SEQ + s0 + arow)) * DM + h * PD;
    int row2 = s0 + arow + 1;
    if (row2 > SEQ - 1) row2 = SEQ - 1;  // clamped row feeds only never-read cells
    const u16* qp2 = Q + ((size_t)(b * SEQ + row2)) * DM + h * PD;
    u16 qa[16] __attribute__((aligned(16)));
    u16 qb[16] __attribute__((aligned(16)));
    *(uint4*)&qa[0] = *(const uint4*)(qp + quad * 8);
    *(uint4*)&qa[8] = *(const uint4*)(qp + 32 + quad * 8);
    *(uint4*)&qb[0] = *(const uint4*)(qp2 + quad * 8);
    *(uint4*)&qb[8] = *(const uint4*)(qp2 + 32 + quad * 8);
    u16 fu[16] __attribute__((aligned(16)));
    u16 fv0[16] __attribute__((aligned(16)));
    u16 fv1[16] __attribute__((aligned(16)));
#pragma unroll
    for (int j = 0; j < 8; ++j) {
      float u0 = pu[quad * 8 + j], u1 = pu[32 + quad * 8 + j];
      float v0 = pv[quad * 8 + j], v1 = pv[32 + quad * 8 + j];
      fu[j] = f2bf((bf2f(qa[j]) + u0) * QS);
      fu[8 + j] = f2bf((bf2f(qa[8 + j]) + u1) * QS);
      fv0[j] = f2bf((bf2f(qa[j]) + v0) * QS);
      fv0[8 + j] = f2bf((bf2f(qa[8 + j]) + v1) * QS);
      fv1[j] = f2bf((bf2f(qb[j]) + v0) * QS);
      fv1[8 + j] = f2bf((bf2f(qb[8 + j]) + v1) * QS);
    }
    __builtin_memcpy(&qu0, &fu[0], 16);
    __builtin_memcpy(&qu1, &fu[8], 16);
    __builtin_memcpy(&qv0a, &fv0[0], 16);
    __builtin_memcpy(&qv1a, &fv0[8], 16);
    __builtin_memcpy(&qv0b, &fv1[0], 16);
    __builtin_memcpy(&qv1b, &fv1[8], 16);
  }

  // all-ones B fragment (bf16 1.0 = 0x3F80) for the l = P . ones MFMA
  bf16x8 onesf;
  {
    u16 onearr[8] __attribute__((aligned(16)));
#pragma unroll
    for (int j = 0; j < 8; ++j) onearr[j] = 0x3F80;
    __builtin_memcpy(&onesf, onearr, 16);
  }

  auto dmaR = [&](int tb0) {
    int tg = tb0 + srow;
    tg = tg < 0 ? 0 : (tg > SEQ - 1 ? SEQ - 1 : tg);
    const u16* gr = Rg + (size_t)tg * DM + h * PD + scol;
    gld16(gr, rvbase);
    gld16(gr + 32, rvbase + 2048);
  };
  auto slice = [&](bf16x8 fa0, bf16x8 fa1, int slotBase, int rowOff, int lo, int hi) {
#pragma unroll
    for (int tt = 0; tt < 4; ++tt) {
      f32x4 pacc = {};
      bf16x8 b0 = *(const bf16x8*)&RVs[kb0 + tt * 512];
      bf16x8 b1 = *(const bf16x8*)&RVs[kb0 + tt * 512 + 2048];
      pacc = __builtin_amdgcn_mfma_f32_16x16x32_bf16(fa0, b0, pacc, 0, 0, 0);
      pacc = __builtin_amdgcn_mfma_f32_16x16x32_bf16(fa1, b1, pacc, 0, 0, 0);
      int rloc = tt * 16 + l16;
      bool ok = (rloc >= lo) & (rloc <= hi);
      u32 w0 = ok ? pack2(pacc[0], pacc[1]) : 0u;
      u32 w1 = ok ? pack2(pacc[2], pacc[3]) : 0u;
      int prow = (slotBase + rloc + rowOff) & 127;
      *(u32*)&Bb[prow * 66 + sl_base] = w0;
      *(u32*)&Bb[prow * 66 + sl_base + 2] = w1;
    }
  };

  f32x4 lacc = {};
  f32x4 oacc[4] = {};

  // ---- warmup: pass0 slice a=0 (rows U in [0,63], always valid) ----
  dmaR(SEQ - 65 - s0);
  __syncthreads();  // R landed
  slice(qv0a, qv1a, 0, 0, 0, 63);

  for (int j0 = 0; j0 < SEQ; j0 += 64) {
    int a1 = (j0 >> 6) + 1;
    int slot = (a1 & 1) << 6;
    bool p0n = (j0 <= s0);
    bool p1n = (j0 >= s0);
    __syncthreads();  // prev PV / warmup LDS reads done
    {
      const u16* gk = Kg + (size_t)(b * SEQ + j0 + srow) * DM + h * PD + scol;
      gld16(gk, kbase);
      gld16(gk + 32, kbase + 2048);
    }
    dmaR((p0n ? (SEQ - 65 - s0) : (-65 - s0)) + 64 * a1);
    __syncthreads();  // K + R landed

    // content scores -> C-layout registers
    f32x4 acc[4];
#pragma unroll
    for (int tn = 0; tn < 4; ++tn) {
      f32x4 a = {};
      bf16x8 b0 = *(const bf16x8*)&KP[kb0 + tn * 512];
      bf16x8 b1 = *(const bf16x8*)&KP[kb0 + tn * 512 + 2048];
      a = __builtin_amdgcn_mfma_f32_16x16x32_bf16(qu0, b0, a, 0, 0, 0);
      a = __builtin_amdgcn_mfma_f32_16x16x32_bf16(qu1, b1, a, 0, 0, 0);
      acc[tn] = a;
    }

    if (p0n) slice(qv0a, qv1a, slot, 0, 0, s0 + 64 - 64 * a1);
    if (p0n && p1n) {  // diagonal tile only: restage R for pass1 (also orders stores)
      __syncthreads();
      dmaR(64 * a1 - s0 - 65);
      __syncthreads();
    }
    if (p1n) slice(qv0b, qv1b, slot, 1, s0 + 65 - 64 * a1, 63);
    __syncthreads();  // band stores visible; RVs frag reads done

    // V DMA (drains at the pre-PV barrier, overlaps gather/softmax VALU)
    {
      const u16* gv = Vtg + ((size_t)(b * NH + h) * PD + srow) * SEQ + j0 + scol;
      gld16(gv, rvbase);
      gld16(gv + 32, rvbase + 2048);
    }

    // gather-add the shifted positional scores — unpredicated, single formula
    int g0 = l16 - sl_base + 64 + j0;
#pragma unroll
    for (int tn = 0; tn < 4; ++tn) {
#pragma unroll
      for (int r = 0; r < 4; ++r) {
        int rl = (g0 + tn * 16 - r) & 127;
        acc[tn][r] += bf2f(Bb[rl * 66 + sl_base + r]);
      }
    }

    // fixed-base softmax: P = exp2(S') directly; l via MFMA below
#pragma unroll
    for (int r = 0; r < 4; ++r) {
      u32 w0 = pack2(EXP2(acc[0][r]), EXP2(acc[1][r]));
      u32 w1 = pack2(EXP2(acc[2][r]), EXP2(acc[3][r]));
      u16 ec[4] = {(u16)w0, (u16)(w0 >> 16), (u16)w1, (u16)(w1 >> 16)};
      int row = sl_base + r;
      u16* prow_ = KP + row * 72 + l16;
#pragma unroll
      for (int cr = 0; cr < 4; ++cr) {
        int c = (cr + quad) & 3;  // quad-rotated column order: conflict-free banks
        prow_[c * 16] = ec[c];
      }
    }
    __syncthreads();  // V landed + P visible

    // PV — pure MFMA accumulate; l = P . ones rides the matrix pipe too
    {
      bf16x8 pa0 = *(const bf16x8*)&KP[arow * 72 + quad * 8];
      bf16x8 pa1 = *(const bf16x8*)&KP[arow * 72 + 32 + quad * 8];
      lacc = __builtin_amdgcn_mfma_f32_16x16x32_bf16(pa0, onesf, lacc, 0, 0, 0);
      lacc = __builtin_amdgcn_mfma_f32_16x16x32_bf16(pa1, onesf, lacc, 0, 0, 0);
#pragma unroll
      for (int tp = 0; tp < 4; ++tp) {
        bf16x8 b0 = *(const bf16x8*)&RVs[kb0 + tp * 512];
        bf16x8 b1 = *(const bf16x8*)&RVs[kb0 + tp * 512 + 2048];
        oacc[tp] = __builtin_amdgcn_mfma_f32_16x16x32_bf16(pa0, b0, oacc[tp], 0, 0, 0);
        oacc[tp] = __builtin_amdgcn_mfma_f32_16x16x32_bf16(pa1, b1, oacc[tp], 0, 0, 0);
      }
    }
  }

  // epilogue: lacc is already in oacc's C-layout (row = sl_base + r)
  float li[4];
#pragma unroll
  for (int r = 0; r < 4; ++r) li[r] = 1.f / lacc[r];
#pragma unroll
  for (int tp = 0; tp < 4; ++tp) {
    int pcol = tp * 16 + l16;
#pragma unroll
    for (int r = 0; r < 4; ++r) {
      int sg = s0 + sl_base + r;
      O[((size_t)(b * SEQ + sg)) * DM + h * PD + pcol] = f2bf(oacc[tp][r] * li[r]);
    }
  }
}

extern "C" void kernel_launch(void* const* d_in, const int* in_sizes, int n_in,
                              void* d_out, int out_size, void* d_ws, size_t ws_size,
                              hipStream_t stream) {
  (void)in_sizes; (void)n_in; (void)out_size; (void)ws_size;
  const void* x  = d_in[0];
  const void* Wq = d_in[1];
  const void* bq = d_in[2];
  const void* Wk = d_in[3];
  const void* bk = d_in[4];
  const void* Wv = d_in[5];
  const void* bv = d_in[6];
  const void* Wp = d_in[7];
  const void* bp = d_in[8];
  const void* Wo = d_in[9];
  const void* bo = d_in[10];
  const void* u  = d_in[11];
  const void* v  = d_in[12];

  char* base = (char*)d_ws;
  int* flag = (int*)base;
  float* pf = (float*)(base + 64);                       // 7168 floats
  u16* wbase = (u16*)(base + 64 + 7168 * 4);
  u16* WT   = wbase;                                     // 5M elems
  u16* xb   = WT + (size_t)5 * DM * DM;                  // 4M (aliased: attn out)
  u16* sinb = xb + (size_t)2 * SEQ * DM;                 // 2M
  u16* Qb   = sinb + (size_t)SEQ * DM;                   // 4M
  u16* Kb   = Qb + (size_t)2 * SEQ * DM;                 // 4M
  u16* Vtb  = Kb + (size_t)2 * SEQ * DM;                 // 4M (Vt direct from gemm)
  u16* Rb   = Vtb + (size_t)2 * SEQ * DM;                // 2M
  u16* Ab   = xb;   // x consumed by qkv gemm before attention writes here

  // one fused preprocessing launch (detect + convert_x + sinusoid + transpose5 + params)
  PrepArgs pa;
  pa.x = x;
  pa.w0 = Wq; pa.w1 = Wk; pa.w2 = Wv; pa.w3 = Wp; pa.w4 = Wo;
  pa.p0 = bq; pa.p1 = bk; pa.p2 = bv; pa.p3 = bp; pa.p4 = bo; pa.p5 = u; pa.p6 = v;
  prep_kernel<<<7452, 256, 0, stream>>>(pa, xb, sinb, WT, pf, flag);

  // merged QKV(+R) GEMM: by 0..31 = x @ {Wq,Wk,Wv} (shared-A), by 32..47 = sin @ Wp
  qkv_kernel<<<dim3(16, 48), 256, 0, stream>>>(xb, sinb, WT, pf, Qb, Kb, Vtb, Rb);

  attn_kernel<<<dim3(1024), 256, 0, stream>>>(Qb, Kb, Vtb, Rb, pf, Ab);

  GemmArgs fo;
  fo.A = Ab; fo.A3 = Ab;
  fo.Bt0 = WT + (size_t)4 * DM * DM; fo.Bt1 = fo.Bt0; fo.Bt2 = fo.Bt0; fo.Bt3 = fo.Bt0;
  fo.b0 = pf + 4096; fo.b1 = fo.b0; fo.b2 = fo.b0; fo.b3 = fo.b0;
  fo.C0 = d_out; fo.C1 = d_out; fo.C2 = d_out; fo.C3 = d_out;
  fo.N = DM; fo.K = DM; fo.M3 = 0; fo.flag = flag; fo.outFp32 = 1; fo.vtrans = 0;
  gemm_bt_kernel<<<dim3(8, 32, 1), 256, 0, stream>>>(fo);
}

// Round 12
// 283.537 us; speedup vs baseline: 1.0244x; 1.0034x over previous
//
#include <hip/hip_runtime.h>
#include <hip/hip_bf16.h>

typedef unsigned short u16;
typedef unsigned int u32;
typedef __bf16 bf16x8 __attribute__((ext_vector_type(8)));
typedef float f32x4 __attribute__((ext_vector_type(4)));

#define SEQ 2048
#define NH 16
#define PD 64
#define DM 1024

#if __has_builtin(__builtin_amdgcn_exp2f)
#define EXP2(x) __builtin_amdgcn_exp2f(x)
#else
#define EXP2(x) __expf((x) * 0.6931471805599453f)
#endif

__device__ __forceinline__ float bf2f(u16 s) {
  u32 t = ((u32)s) << 16;
  float f;
  __builtin_memcpy(&f, &t, 4);
  return f;
}
__device__ __forceinline__ u16 f2bf(float f) {
  u32 x;
  __builtin_memcpy(&x, &f, 4);
  x = (x + 0x7fffu + ((x >> 16) & 1u)) >> 16;
  return (u16)x;
}
__device__ __forceinline__ u32 pack2(float a, float b) {
  __hip_bfloat162 h = __float22bfloat162_rn(float2{a, b});
  u32 r;
  __builtin_memcpy(&r, &h, 4);
  return r;
}
// async global -> LDS, 16B per lane. lds dest = wave-uniform base + lane*16B.
__device__ __forceinline__ void gld16(const u16* g, u16* l) {
  __builtin_amdgcn_global_load_lds(
      (const __attribute__((address_space(1))) unsigned int*)(g),
      (__attribute__((address_space(3))) unsigned int*)(l), 16, 0, 0);
}

// Monotone grid barrier: co-residency guaranteed by launch_bounds + grid <= k*256.
// Counter memset to 0 each launch (capture-safe hipMemsetAsync). AGENT-scope
// acq_rel atomics + threadfence give cross-XCD visibility (guide G16).
__device__ __forceinline__ void grid_barrier(int* cnt, int nblk) {
  __syncthreads();
  if (threadIdx.x == 0) {
    __threadfence();
    int old = __hip_atomic_fetch_add(cnt, 1, __ATOMIC_ACQ_REL, __HIP_MEMORY_SCOPE_AGENT);
    int target = (old / nblk + 1) * nblk;
    while (__hip_atomic_load(cnt, __ATOMIC_ACQUIRE, __HIP_MEMORY_SCOPE_AGENT) < target) {
      __builtin_amdgcn_s_sleep(8);
    }
  }
  __syncthreads();
}

// ---------------- args ----------------
struct PrepArgs {
  const void* x;
  const void* w0; const void* w1; const void* w2; const void* w3; const void* w4;
  const void* p0; const void* p1; const void* p2; const void* p3; const void* p4;
  const void* p5; const void* p6;
};

// =====================================================================================
// MERGED KERNEL 1: prep (grid-stride) -> grid barrier -> QKV(+R) GEMM
// 768 blocks, 3 blocks/CU by construction (LDS 31.7KB, launch_bounds(256,3)).
// =====================================================================================
__global__ __launch_bounds__(256, 3) void prep_qkv_kernel(
    PrepArgs pa,
    u16* __restrict__ xb, u16* __restrict__ sinb, u16* __restrict__ WT,
    float* __restrict__ pf, int* __restrict__ flag, int* __restrict__ cnt,
    u16* __restrict__ Qb, u16* __restrict__ Kb, u16* __restrict__ Vtb,
    u16* __restrict__ Rb) {
  __shared__ int sz[256], sh[256];
  __shared__ u16 t[64][72];
  __shared__ u16 As[128 * 32];
  __shared__ u16 Bs[3 * 64 * 32];
  int tid = threadIdx.x;
  int bid = blockIdx.x;

  // ---- local dtype detect (once per block) ----
  {
    const u16* probe = (const u16*)pa.w0;
    int zeros = 0, huge = 0;
    for (int j = 0; j < 16; ++j) {
      int i = tid * 16 + j;
      u16 v = probe[i];
      int e = (v >> 7) & 0xFF;
      if (((i & 1) == 0) && v == 0) zeros++;
      if (e >= 0x8C) huge++;
    }
    sz[tid] = zeros; sh[tid] = huge;
    __syncthreads();
    for (int s = 128; s > 0; s >>= 1) {
      if (tid < s) { sz[tid] += sz[tid + s]; sh[tid] += sh[tid + s]; }
      __syncthreads();
    }
  }
  int f = (sz[0] > 1024 || sh[0] > 200) ? 1 : 0;
  if (bid == 0 && tid == 0) *flag = f;

  // ---- PHASE 1: prep, grid-stride over 7452 units ----
  for (int id = bid; id < 7452; id += 768) {
    if (id < 4096) {
      int i = (id * 256 + tid) * 4;
      if (f) {
        float4 fv = *(const float4*)((const float*)pa.x + i);
        u16 o[4] __attribute__((aligned(8))) = {f2bf(fv.x), f2bf(fv.y), f2bf(fv.z), f2bf(fv.w)};
        *(uint2*)(xb + i) = *(const uint2*)o;
      } else {
        *(uint2*)(xb + i) = *(const uint2*)((const u16*)pa.x + i);
      }
    } else if (id < 6144) {
      int base = ((id - 4096) * 256 + tid) * 4;
      u16 o[4] __attribute__((aligned(8)));
#pragma unroll
      for (int e = 0; e < 4; ++e) {
        int idx = base + e;
        int s = idx >> 10;
        int i = idx & 1023;
        int j = i & 511;
        float invf = __expf(-(float)j * (9.210340371976184f / 512.0f));
        float ang = (float)s * invf;
        float val = (i < 512) ? __sinf(ang) : __cosf(ang);
        o[e] = f2bf(val);
      }
      *(uint2*)(sinb + base) = *(const uint2*)o;
    } else if (id < 7424) {
      __syncthreads();  // protect t from previous iteration's reads
      int tt = id - 6144;
      int z = tt >> 8;
      int rem = tt & 255;
      const void* src = (z == 0) ? pa.w0 : (z == 1) ? pa.w1 : (z == 2) ? pa.w2
                       : (z == 3) ? pa.w3 : pa.w4;
      u16* out = WT + (size_t)z * DM * DM;
      int r0 = (rem >> 4) * 64, c0 = (rem & 15) * 64;
      int tr = tid >> 2;
      int tc = (tid & 3) * 16;
      if (f) {
        const float* g = (const float*)src + (size_t)(r0 + tr) * DM + c0 + tc;
#pragma unroll
        for (int q = 0; q < 4; ++q) {
          float4 fv = *(const float4*)(g + q * 4);
          t[tr][tc + q * 4 + 0] = f2bf(fv.x);
          t[tr][tc + q * 4 + 1] = f2bf(fv.y);
          t[tr][tc + q * 4 + 2] = f2bf(fv.z);
          t[tr][tc + q * 4 + 3] = f2bf(fv.w);
        }
      } else {
        const uint4* g = (const uint4*)((const u16*)src + (size_t)(r0 + tr) * DM + c0 + tc);
        uint4 a = g[0], bb = g[1];
        *(uint4*)&t[tr][tc] = a;
        *(uint4*)&t[tr][tc + 8] = bb;
      }
      __syncthreads();
      u16 tmp[16] __attribute__((aligned(16)));
#pragma unroll
      for (int jj = 0; jj < 16; ++jj) tmp[jj] = t[tc + jj][tr];
      uint4* o = (uint4*)(out + (size_t)(c0 + tr) * DM + r0 + tc);
      o[0] = *(const uint4*)&tmp[0];
      o[1] = *(const uint4*)&tmp[8];
    } else {
      int idx = (id - 7424) * 256 + tid;
      int seg = idx >> 10, off = idx & 1023;
      const void* s = (seg == 0) ? pa.p0 : (seg == 1) ? pa.p1 : (seg == 2) ? pa.p2
                     : (seg == 3) ? pa.p3 : (seg == 4) ? pa.p4 : (seg == 5) ? pa.p5 : pa.p6;
      pf[idx] = f ? ((const float*)s)[off] : bf2f(((const u16*)s)[off]);
    }
  }

  grid_barrier(cnt, 768);

  // ---- PHASE 2: merged QKV(+R) GEMM (body verbatim from qkv_kernel) ----
  int wave = tid >> 6, lane = tid & 63;
  int quad = lane >> 4, l16 = lane & 15;
  int bx = bid & 15, by = bid >> 4;
  bool isR = by >= 32;
  int m0 = (isR ? (by - 32) : by) * 128;
  int n0 = bx * 64;
  int wm = (wave >> 1) * 64, wn = (wave & 1) * 32;

  int trow = tid >> 2;
  int tcol = ((tid & 3) ^ ((tid >> 3) & 3)) * 8;
  const u16* A = isR ? sinb : xb;
  const u16* ga = A + (size_t)(m0 + trow) * DM + tcol;
  const u16* gb = WT + (isR ? (size_t)3 * DM * DM : 0) + (size_t)(n0 + trow) * DM + tcol;
  u16* lwa = As + wave * 512;
  u16* lwb = Bs + wave * 512;
  int slotx = (quad ^ ((l16 >> 1) & 3)) * 8;

  if (!isR) {
    f32x4 acc[3][4][2] = {};
    for (int k0 = 0; k0 < DM; k0 += 32) {
      __syncthreads();
      gld16(ga + k0, lwa);
      gld16(ga + (size_t)64 * DM + k0, lwa + 2048);
      gld16(gb + k0, lwb);
      gld16(gb + (size_t)DM * DM + k0, lwb + 2048);
      gld16(gb + (size_t)2 * DM * DM + k0, lwb + 4096);
      __syncthreads();
      bf16x8 af[4];
#pragma unroll
      for (int i = 0; i < 4; ++i)
        af[i] = *(const bf16x8*)&As[(wm + i * 16 + l16) * 32 + slotx];
#pragma unroll
      for (int z = 0; z < 3; ++z) {
        bf16x8 b0 = *(const bf16x8*)&Bs[z * 2048 + (wn + l16) * 32 + slotx];
        bf16x8 b1 = *(const bf16x8*)&Bs[z * 2048 + (wn + 16 + l16) * 32 + slotx];
#pragma unroll
        for (int tm = 0; tm < 4; ++tm) {
          acc[z][tm][0] = __builtin_amdgcn_mfma_f32_16x16x32_bf16(af[tm], b0, acc[z][tm][0], 0, 0, 0);
          acc[z][tm][1] = __builtin_amdgcn_mfma_f32_16x16x32_bf16(af[tm], b1, acc[z][tm][1], 0, 0, 0);
        }
      }
    }
#pragma unroll
    for (int tm = 0; tm < 4; ++tm) {
      int row = m0 + wm + tm * 16 + quad * 4;
#pragma unroll
      for (int tn = 0; tn < 2; ++tn) {
        int col = n0 + wn + tn * 16 + l16;
        float bq = pf[col], bk = pf[1024 + col], bv = pf[2048 + col];
#pragma unroll
        for (int r = 0; r < 4; ++r) {
          Qb[(size_t)(row + r) * DM + col] = f2bf(acc[0][tm][tn][r] + bq);
          Kb[(size_t)(row + r) * DM + col] = f2bf(acc[1][tm][tn][r] + bk);
        }
        u16 o4[4] __attribute__((aligned(8)));
#pragma unroll
        for (int r = 0; r < 4; ++r) o4[r] = f2bf(acc[2][tm][tn][r] + bv);
        int bq_ = row >> 11, s = row & 2047;
        *(uint2*)(Vtb + ((size_t)(bq_ * 1024 + col)) * 2048 + s) = *(const uint2*)o4;
      }
    }
  } else {
    f32x4 acc[4][2] = {};
    for (int k0 = 0; k0 < DM; k0 += 32) {
      __syncthreads();
      gld16(ga + k0, lwa);
      gld16(ga + (size_t)64 * DM + k0, lwa + 2048);
      gld16(gb + k0, lwb);
      __syncthreads();
      bf16x8 af[4];
#pragma unroll
      for (int i = 0; i < 4; ++i)
        af[i] = *(const bf16x8*)&As[(wm + i * 16 + l16) * 32 + slotx];
      bf16x8 b0 = *(const bf16x8*)&Bs[(wn + l16) * 32 + slotx];
      bf16x8 b1 = *(const bf16x8*)&Bs[(wn + 16 + l16) * 32 + slotx];
#pragma unroll
      for (int tm = 0; tm < 4; ++tm) {
        acc[tm][0] = __builtin_amdgcn_mfma_f32_16x16x32_bf16(af[tm], b0, acc[tm][0], 0, 0, 0);
        acc[tm][1] = __builtin_amdgcn_mfma_f32_16x16x32_bf16(af[tm], b1, acc[tm][1], 0, 0, 0);
      }
    }
#pragma unroll
    for (int tm = 0; tm < 4; ++tm) {
      int row = m0 + wm + tm * 16 + quad * 4;
#pragma unroll
      for (int tn = 0; tn < 2; ++tn) {
        int col = n0 + wn + tn * 16 + l16;
        float br = pf[3072 + col];
#pragma unroll
        for (int r = 0; r < 4; ++r)
          Rb[(size_t)(row + r) * DM + col] = f2bf(acc[tm][tn][r] + br);
      }
    }
  }
}

// =====================================================================================
// MERGED KERNEL 2: attn (1024 tiles) -> grid barrier -> fo GEMM (64x64 tiles, 1024)
// 1024 blocks, 4 blocks/CU by construction (LDS 34.3KB, launch_bounds(256,4)).
// =====================================================================================
__global__ __launch_bounds__(256, 4) void attn_fo_kernel(
    const u16* __restrict__ Q, const u16* __restrict__ Kg,
    const u16* __restrict__ Vtg, const u16* __restrict__ Rg,
    const float* __restrict__ pf,
    u16* __restrict__ O, const u16* __restrict__ WT4,
    const int* __restrict__ flag, int* __restrict__ cnt,
    void* __restrict__ dout) {
  __shared__ __align__(16) u16 KP[64 * 72];   // K blocked / P ; fo: A+B tiles
  __shared__ __align__(16) u16 RVs[4096];     // R slice / V blocked
  __shared__ __align__(16) u16 Bb[128 * 66];  // shared pos band

  int tid = threadIdx.x, wave = tid >> 6, lane = tid & 63;
  int quad = lane >> 4, l16 = lane & 15;
  int id = blockIdx.x;
  int bh = (id & 7) + ((id >> 8) << 3);
  int s0 = ((id >> 3) & 31) * 64;
  int b = bh >> 4, h = bh & 15;
  const float* pu = pf + 5 * 1024 + h * PD;
  const float* pv = pf + 6 * 1024 + h * PD;

  int arow = wave * 16 + l16;
  int sl_base = wave * 16 + quad * 4;

  int srow = wave * 16 + (lane >> 2);
  int scol = ((lane & 3) ^ ((lane >> 3) & 3)) * 8;
  u16* kbase = KP + wave * 512;
  u16* rvbase = RVs + wave * 512;
  int kb0 = l16 * 32 + (quad ^ ((l16 >> 1) & 3)) * 8;

  // ---- prologue: Q fragments, pre-scaled by (1/8)*log2(e) ----
  const float QS = 0.18033688011112042f;
  bf16x8 qu0, qu1, qv0a, qv1a, qv0b, qv1b;
  {
    const u16* qp = Q + ((size_t)(b * SEQ + s0 + arow)) * DM + h * PD;
    int row2 = s0 + arow + 1;
    if (row2 > SEQ - 1) row2 = SEQ - 1;
    const u16* qp2 = Q + ((size_t)(b * SEQ + row2)) * DM + h * PD;
    u16 qa[16] __attribute__((aligned(16)));
    u16 qb[16] __attribute__((aligned(16)));
    *(uint4*)&qa[0] = *(const uint4*)(qp + quad * 8);
    *(uint4*)&qa[8] = *(const uint4*)(qp + 32 + quad * 8);
    *(uint4*)&qb[0] = *(const uint4*)(qp2 + quad * 8);
    *(uint4*)&qb[8] = *(const uint4*)(qp2 + 32 + quad * 8);
    u16 fu[16] __attribute__((aligned(16)));
    u16 fv0[16] __attribute__((aligned(16)));
    u16 fv1[16] __attribute__((aligned(16)));
#pragma unroll
    for (int j = 0; j < 8; ++j) {
      float u0 = pu[quad * 8 + j], u1 = pu[32 + quad * 8 + j];
      float v0 = pv[quad * 8 + j], v1 = pv[32 + quad * 8 + j];
      fu[j] = f2bf((bf2f(qa[j]) + u0) * QS);
      fu[8 + j] = f2bf((bf2f(qa[8 + j]) + u1) * QS);
      fv0[j] = f2bf((bf2f(qa[j]) + v0) * QS);
      fv0[8 + j] = f2bf((bf2f(qa[8 + j]) + v1) * QS);
      fv1[j] = f2bf((bf2f(qb[j]) + v0) * QS);
      fv1[8 + j] = f2bf((bf2f(qb[8 + j]) + v1) * QS);
    }
    __builtin_memcpy(&qu0, &fu[0], 16);
    __builtin_memcpy(&qu1, &fu[8], 16);
    __builtin_memcpy(&qv0a, &fv0[0], 16);
    __builtin_memcpy(&qv1a, &fv0[8], 16);
    __builtin_memcpy(&qv0b, &fv1[0], 16);
    __builtin_memcpy(&qv1b, &fv1[8], 16);
  }

  bf16x8 onesf;
  {
    u16 onearr[8] __attribute__((aligned(16)));
#pragma unroll
    for (int j = 0; j < 8; ++j) onearr[j] = 0x3F80;
    __builtin_memcpy(&onesf, onearr, 16);
  }

  auto dmaR = [&](int tb0) {
    int tg = tb0 + srow;
    tg = tg < 0 ? 0 : (tg > SEQ - 1 ? SEQ - 1 : tg);
    const u16* gr = Rg + (size_t)tg * DM + h * PD + scol;
    gld16(gr, rvbase);
    gld16(gr + 32, rvbase + 2048);
  };
  auto slice = [&](bf16x8 fa0, bf16x8 fa1, int slotBase, int rowOff, int lo, int hi) {
#pragma unroll
    for (int tt = 0; tt < 4; ++tt) {
      f32x4 pacc = {};
      bf16x8 b0 = *(const bf16x8*)&RVs[kb0 + tt * 512];
      bf16x8 b1 = *(const bf16x8*)&RVs[kb0 + tt * 512 + 2048];
      pacc = __builtin_amdgcn_mfma_f32_16x16x32_bf16(fa0, b0, pacc, 0, 0, 0);
      pacc = __builtin_amdgcn_mfma_f32_16x16x32_bf16(fa1, b1, pacc, 0, 0, 0);
      int rloc = tt * 16 + l16;
      bool ok = (rloc >= lo) & (rloc <= hi);
      u32 w0 = ok ? pack2(pacc[0], pacc[1]) : 0u;
      u32 w1 = ok ? pack2(pacc[2], pacc[3]) : 0u;
      int prow = (slotBase + rloc + rowOff) & 127;
      *(u32*)&Bb[prow * 66 + sl_base] = w0;
      *(u32*)&Bb[prow * 66 + sl_base + 2] = w1;
    }
  };

  f32x4 lacc = {};
  f32x4 oacc[4] = {};

  dmaR(SEQ - 65 - s0);
  __syncthreads();
  slice(qv0a, qv1a, 0, 0, 0, 63);

  for (int j0 = 0; j0 < SEQ; j0 += 64) {
    int a1 = (j0 >> 6) + 1;
    int slot = (a1 & 1) << 6;
    bool p0n = (j0 <= s0);
    bool p1n = (j0 >= s0);
    __syncthreads();
    {
      const u16* gk = Kg + (size_t)(b * SEQ + j0 + srow) * DM + h * PD + scol;
      gld16(gk, kbase);
      gld16(gk + 32, kbase + 2048);
    }
    dmaR((p0n ? (SEQ - 65 - s0) : (-65 - s0)) + 64 * a1);
    __syncthreads();

    f32x4 acc[4];
#pragma unroll
    for (int tn = 0; tn < 4; ++tn) {
      f32x4 a = {};
      bf16x8 b0 = *(const bf16x8*)&KP[kb0 + tn * 512];
      bf16x8 b1 = *(const bf16x8*)&KP[kb0 + tn * 512 + 2048];
      a = __builtin_amdgcn_mfma_f32_16x16x32_bf16(qu0, b0, a, 0, 0, 0);
      a = __builtin_amdgcn_mfma_f32_16x16x32_bf16(qu1, b1, a, 0, 0, 0);
      acc[tn] = a;
    }

    if (p0n) slice(qv0a, qv1a, slot, 0, 0, s0 + 64 - 64 * a1);
    if (p0n && p1n) {
      __syncthreads();
      dmaR(64 * a1 - s0 - 65);
      __syncthreads();
    }
    if (p1n) slice(qv0b, qv1b, slot, 1, s0 + 65 - 64 * a1, 63);
    __syncthreads();

    {
      const u16* gv = Vtg + ((size_t)(b * NH + h) * PD + srow) * SEQ + j0 + scol;
      gld16(gv, rvbase);
      gld16(gv + 32, rvbase + 2048);
    }

    int g0 = l16 - sl_base + 64 + j0;
#pragma unroll
    for (int tn = 0; tn < 4; ++tn) {
#pragma unroll
      for (int r = 0; r < 4; ++r) {
        int rl = (g0 + tn * 16 - r) & 127;
        acc[tn][r] += bf2f(Bb[rl * 66 + sl_base + r]);
      }
    }

#pragma unroll
    for (int r = 0; r < 4; ++r) {
      u32 w0 = pack2(EXP2(acc[0][r]), EXP2(acc[1][r]));
      u32 w1 = pack2(EXP2(acc[2][r]), EXP2(acc[3][r]));
      u16 ec[4] = {(u16)w0, (u16)(w0 >> 16), (u16)w1, (u16)(w1 >> 16)};
      int row = sl_base + r;
      u16* prow_ = KP + row * 72 + l16;
#pragma unroll
      for (int cr = 0; cr < 4; ++cr) {
        int c = (cr + quad) & 3;
        prow_[c * 16] = ec[c];
      }
    }
    __syncthreads();

    {
      bf16x8 pa0 = *(const bf16x8*)&KP[arow * 72 + quad * 8];
      bf16x8 pa1 = *(const bf16x8*)&KP[arow * 72 + 32 + quad * 8];
      lacc = __builtin_amdgcn_mfma_f32_16x16x32_bf16(pa0, onesf, lacc, 0, 0, 0);
      lacc = __builtin_amdgcn_mfma_f32_16x16x32_bf16(pa1, onesf, lacc, 0, 0, 0);
#pragma unroll
      for (int tp = 0; tp < 4; ++tp) {
        bf16x8 b0 = *(const bf16x8*)&RVs[kb0 + tp * 512];
        bf16x8 b1 = *(const bf16x8*)&RVs[kb0 + tp * 512 + 2048];
        oacc[tp] = __builtin_amdgcn_mfma_f32_16x16x32_bf16(pa0, b0, oacc[tp], 0, 0, 0);
        oacc[tp] = __builtin_amdgcn_mfma_f32_16x16x32_bf16(pa1, b1, oacc[tp], 0, 0, 0);
      }
    }
  }

  float li[4];
#pragma unroll
  for (int r = 0; r < 4; ++r) li[r] = 1.f / lacc[r];
#pragma unroll
  for (int tp = 0; tp < 4; ++tp) {
    int pcol = tp * 16 + l16;
#pragma unroll
    for (int r = 0; r < 4; ++r) {
      int sg = s0 + sl_base + r;
      O[((size_t)(b * SEQ + sg)) * DM + h * PD + pcol] = f2bf(oacc[tp][r] * li[r]);
    }
  }

  grid_barrier(cnt, 1024);

  // ---- PHASE 2: fo GEMM, 64x64 tile per block (1024 tiles), LDS reuses KP/Bb ----
  {
    bool f32o = (*flag != 0);
    int mt = id >> 4, nt = id & 15;
    int m0f = mt * 64, n0f = nt * 64;
    int wm2 = (wave >> 1) * 32, wn2 = (wave & 1) * 32;
    int trow = tid >> 2;
    int tcol = ((tid & 3) ^ ((tid >> 3) & 3)) * 8;
    const u16* gaF = O + (size_t)(m0f + trow) * DM + tcol;
    const u16* gbF = WT4 + (size_t)(n0f + trow) * DM + tcol;
    u16* lwaF = KP + wave * 512;   // A tile: KP[0..2047]
    u16* lwbF = Bb + wave * 512;   // B tile: Bb[0..2047]
    int slotx = (quad ^ ((l16 >> 1) & 3)) * 8;

    f32x4 acc2[2][2] = {};
    for (int k0 = 0; k0 < DM; k0 += 32) {
      __syncthreads();
      gld16(gaF + k0, lwaF);
      gld16(gbF + k0, lwbF);
      __syncthreads();
      bf16x8 af2[2], bf2v[2];
#pragma unroll
      for (int i = 0; i < 2; ++i) {
        af2[i] = *(const bf16x8*)&KP[(wm2 + i * 16 + l16) * 32 + slotx];
        bf2v[i] = *(const bf16x8*)&Bb[(wn2 + i * 16 + l16) * 32 + slotx];
      }
#pragma unroll
      for (int tm = 0; tm < 2; ++tm)
#pragma unroll
        for (int tn = 0; tn < 2; ++tn)
          acc2[tm][tn] = __builtin_amdgcn_mfma_f32_16x16x32_bf16(af2[tm], bf2v[tn], acc2[tm][tn], 0, 0, 0);
    }
#pragma unroll
    for (int tm = 0; tm < 2; ++tm) {
      int row = m0f + wm2 + tm * 16 + quad * 4;
#pragma unroll
      for (int tn = 0; tn < 2; ++tn) {
        int col = n0f + wn2 + tn * 16 + l16;
        float bv = pf[4096 + col];
#pragma unroll
        for (int r = 0; r < 4; ++r) {
          float val = acc2[tm][tn][r] + bv;
          if (f32o) ((float*)dout)[(size_t)(row + r) * DM + col] = val;
          else ((u16*)dout)[(size_t)(row + r) * DM + col] = f2bf(val);
        }
      }
    }
  }
}

// =====================================================================================
// FALLBACK kernels (proven 4-launch path) — used only if occupancy guarantee fails
// =====================================================================================
__global__ __launch_bounds__(256) void prep_kernel(PrepArgs pa,
                                                   u16* __restrict__ xb,
                                                   u16* __restrict__ sinb,
                                                   u16* __restrict__ WT,
                                                   float* __restrict__ pf,
                                                   int* __restrict__ flag) {
  __shared__ int sz[256], sh[256];
  __shared__ u16 t[64][72];
  int tid = threadIdx.x;
  {
    const u16* probe = (const u16*)pa.w0;
    int zeros = 0, huge = 0;
    for (int j = 0; j < 16; ++j) {
      int i = tid * 16 + j;
      u16 v = probe[i];
      int e = (v >> 7) & 0xFF;
      if (((i & 1) == 0) && v == 0) zeros++;
      if (e >= 0x8C) huge++;
    }
    sz[tid] = zeros; sh[tid] = huge;
    __syncthreads();
    for (int s = 128; s > 0; s >>= 1) {
      if (tid < s) { sz[tid] += sz[tid + s]; sh[tid] += sh[tid + s]; }
      __syncthreads();
    }
  }
  int f = (sz[0] > 1024 || sh[0] > 200) ? 1 : 0;
  int id = blockIdx.x;
  if (id == 0 && tid == 0) *flag = f;

  if (id < 4096) {
    int i = (id * 256 + tid) * 4;
    if (f) {
      float4 fv = *(const float4*)((const float*)pa.x + i);
      u16 o[4] __attribute__((aligned(8))) = {f2bf(fv.x), f2bf(fv.y), f2bf(fv.z), f2bf(fv.w)};
      *(uint2*)(xb + i) = *(const uint2*)o;
    } else {
      *(uint2*)(xb + i) = *(const uint2*)((const u16*)pa.x + i);
    }
  } else if (id < 6144) {
    int base = ((id - 4096) * 256 + tid) * 4;
    u16 o[4] __attribute__((aligned(8)));
#pragma unroll
    for (int e = 0; e < 4; ++e) {
      int idx = base + e;
      int s = idx >> 10;
      int i = idx & 1023;
      int j = i & 511;
      float invf = __expf(-(float)j * (9.210340371976184f / 512.0f));
      float ang = (float)s * invf;
      float val = (i < 512) ? __sinf(ang) : __cosf(ang);
      o[e] = f2bf(val);
    }
    *(uint2*)(sinb + base) = *(const uint2*)o;
  } else if (id < 7424) {
    int tt = id - 6144;
    int z = tt >> 8;
    int rem = tt & 255;
    const void* src = (z == 0) ? pa.w0 : (z == 1) ? pa.w1 : (z == 2) ? pa.w2
                     : (z == 3) ? pa.w3 : pa.w4;
    u16* out = WT + (size_t)z * DM * DM;
    int r0 = (rem >> 4) * 64, c0 = (rem & 15) * 64;
    int tr = tid >> 2;
    int tc = (tid & 3) * 16;
    if (f) {
      const float* g = (const float*)src + (size_t)(r0 + tr) * DM + c0 + tc;
#pragma unroll
      for (int q = 0; q < 4; ++q) {
        float4 fv = *(const float4*)(g + q * 4);
        t[tr][tc + q * 4 + 0] = f2bf(fv.x);
        t[tr][tc + q * 4 + 1] = f2bf(fv.y);
        t[tr][tc + q * 4 + 2] = f2bf(fv.z);
        t[tr][tc + q * 4 + 3] = f2bf(fv.w);
      }
    } else {
      const uint4* g = (const uint4*)((const u16*)src + (size_t)(r0 + tr) * DM + c0 + tc);
      uint4 a = g[0], bb = g[1];
      *(uint4*)&t[tr][tc] = a;
      *(uint4*)&t[tr][tc + 8] = bb;
    }
    __syncthreads();
    u16 tmp[16] __attribute__((aligned(16)));
#pragma unroll
    for (int jj = 0; jj < 16; ++jj) tmp[jj] = t[tc + jj][tr];
    uint4* o = (uint4*)(out + (size_t)(c0 + tr) * DM + r0 + tc);
    o[0] = *(const uint4*)&tmp[0];
    o[1] = *(const uint4*)&tmp[8];
  } else {
    int idx = (id - 7424) * 256 + tid;
    int seg = idx >> 10, off = idx & 1023;
    const void* s = (seg == 0) ? pa.p0 : (seg == 1) ? pa.p1 : (seg == 2) ? pa.p2
                   : (seg == 3) ? pa.p3 : (seg == 4) ? pa.p4 : (seg == 5) ? pa.p5 : pa.p6;
    pf[idx] = f ? ((const float*)s)[off] : bf2f(((const u16*)s)[off]);
  }
}

__global__ __launch_bounds__(256, 3) void qkv_kernel(
    const u16* __restrict__ xb, const u16* __restrict__ sinb,
    const u16* __restrict__ WT, const float* __restrict__ pf,
    u16* __restrict__ Qb, u16* __restrict__ Kb, u16* __restrict__ Vtb,
    u16* __restrict__ Rb) {
  __shared__ u16 As[128 * 32];
  __shared__ u16 Bs[3 * 64 * 32];
  int tid = threadIdx.x;
  int wave = tid >> 6, lane = tid & 63;
  int quad = lane >> 4, l16 = lane & 15;
  int bx = blockIdx.x, by = blockIdx.y;
  bool isR = by >= 32;
  int m0 = (isR ? (by - 32) : by) * 128;
  int n0 = bx * 64;
  int wm = (wave >> 1) * 64, wn = (wave & 1) * 32;

  int trow = tid >> 2;
  int tcol = ((tid & 3) ^ ((tid >> 3) & 3)) * 8;
  const u16* A = isR ? sinb : xb;
  const u16* ga = A + (size_t)(m0 + trow) * DM + tcol;
  const u16* gb = WT + (isR ? (size_t)3 * DM * DM : 0) + (size_t)(n0 + trow) * DM + tcol;
  u16* lwa = As + wave * 512;
  u16* lwb = Bs + wave * 512;
  int slotx = (quad ^ ((l16 >> 1) & 3)) * 8;

  if (!isR) {
    f32x4 acc[3][4][2] = {};
    for (int k0 = 0; k0 < DM; k0 += 32) {
      __syncthreads();
      gld16(ga + k0, lwa);
      gld16(ga + (size_t)64 * DM + k0, lwa + 2048);
      gld16(gb + k0, lwb);
      gld16(gb + (size_t)DM * DM + k0, lwb + 2048);
      gld16(gb + (size_t)2 * DM * DM + k0, lwb + 4096);
      __syncthreads();
      bf16x8 af[4];
#pragma unroll
      for (int i = 0; i < 4; ++i)
        af[i] = *(const bf16x8*)&As[(wm + i * 16 + l16) * 32 + slotx];
#pragma unroll
      for (int z = 0; z < 3; ++z) {
        bf16x8 b0 = *(const bf16x8*)&Bs[z * 2048 + (wn + l16) * 32 + slotx];
        bf16x8 b1 = *(const bf16x8*)&Bs[z * 2048 + (wn + 16 + l16) * 32 + slotx];
#pragma unroll
        for (int tm = 0; tm < 4; ++tm) {
          acc[z][tm][0] = __builtin_amdgcn_mfma_f32_16x16x32_bf16(af[tm], b0, acc[z][tm][0], 0, 0, 0);
          acc[z][tm][1] = __builtin_amdgcn_mfma_f32_16x16x32_bf16(af[tm], b1, acc[z][tm][1], 0, 0, 0);
        }
      }
    }
#pragma unroll
    for (int tm = 0; tm < 4; ++tm) {
      int row = m0 + wm + tm * 16 + quad * 4;
#pragma unroll
      for (int tn = 0; tn < 2; ++tn) {
        int col = n0 + wn + tn * 16 + l16;
        float bq = pf[col], bk = pf[1024 + col], bv = pf[2048 + col];
#pragma unroll
        for (int r = 0; r < 4; ++r) {
          Qb[(size_t)(row + r) * DM + col] = f2bf(acc[0][tm][tn][r] + bq);
          Kb[(size_t)(row + r) * DM + col] = f2bf(acc[1][tm][tn][r] + bk);
        }
        u16 o4[4] __attribute__((aligned(8)));
#pragma unroll
        for (int r = 0; r < 4; ++r) o4[r] = f2bf(acc[2][tm][tn][r] + bv);
        int bq_ = row >> 11, s = row & 2047;
        *(uint2*)(Vtb + ((size_t)(bq_ * 1024 + col)) * 2048 + s) = *(const uint2*)o4;
      }
    }
  } else {
    f32x4 acc[4][2] = {};
    for (int k0 = 0; k0 < DM; k0 += 32) {
      __syncthreads();
      gld16(ga + k0, lwa);
      gld16(ga + (size_t)64 * DM + k0, lwa + 2048);
      gld16(gb + k0, lwb);
      __syncthreads();
      bf16x8 af[4];
#pragma unroll
      for (int i = 0; i < 4; ++i)
        af[i] = *(const bf16x8*)&As[(wm + i * 16 + l16) * 32 + slotx];
      bf16x8 b0 = *(const bf16x8*)&Bs[(wn + l16) * 32 + slotx];
      bf16x8 b1 = *(const bf16x8*)&Bs[(wn + 16 + l16) * 32 + slotx];
#pragma unroll
      for (int tm = 0; tm < 4; ++tm) {
        acc[tm][0] = __builtin_amdgcn_mfma_f32_16x16x32_bf16(af[tm], b0, acc[tm][0], 0, 0, 0);
        acc[tm][1] = __builtin_amdgcn_mfma_f32_16x16x32_bf16(af[tm], b1, acc[tm][1], 0, 0, 0);
      }
    }
#pragma unroll
    for (int tm = 0; tm < 4; ++tm) {
      int row = m0 + wm + tm * 16 + quad * 4;
#pragma unroll
      for (int tn = 0; tn < 2; ++tn) {
        int col = n0 + wn + tn * 16 + l16;
        float br = pf[3072 + col];
#pragma unroll
        for (int r = 0; r < 4; ++r)
          Rb[(size_t)(row + r) * DM + col] = f2bf(acc[tm][tn][r] + br);
      }
    }
  }
}

struct GemmArgs {
  const u16* A;  const u16* A3;
  const u16* Bt0; const u16* Bt1; const u16* Bt2; const u16* Bt3;
  const float* b0; const float* b1; const float* b2; const float* b3;
  void* C0; void* C1; void* C2; void* C3;
  int N, K, M3;
  const int* flag; int outFp32; int vtrans;
};

__global__ __launch_bounds__(256, 4) void gemm_bt_kernel(GemmArgs p) {
  __shared__ u16 As[128 * 64];
  __shared__ u16 Bs[128 * 64];
  int z = blockIdx.z;
  if (z == 3 && (int)blockIdx.y * 128 >= p.M3) return;
  const u16* A = (z == 3) ? p.A3 : p.A;
  const u16* Bt = (z == 0) ? p.Bt0 : (z == 1) ? p.Bt1 : (z == 2) ? p.Bt2 : p.Bt3;
  const float* bias = (z == 0) ? p.b0 : (z == 1) ? p.b1 : (z == 2) ? p.b2 : p.b3;
  void* Cv = (z == 0) ? p.C0 : (z == 1) ? p.C1 : (z == 2) ? p.C2 : p.C3;
  int K = p.K, N = p.N;
  bool f32o = p.outFp32 && (*p.flag);
  bool vt = p.vtrans && (z == 2);

  int tid = threadIdx.x;
  int wave = tid >> 6, lane = tid & 63;
  int quad = lane >> 4, l16 = lane & 15;
  int m0 = blockIdx.y * 128, n0 = blockIdx.x * 128;
  int wm = (wave >> 1) * 64, wn = (wave & 1) * 64;

  int trow = tid >> 2;
  int tcol = ((tid & 3) ^ ((tid >> 3) & 3)) * 8;
  const u16* ga = A + (size_t)(m0 + trow) * K + tcol;
  const u16* gb = Bt + (size_t)(n0 + trow) * K + tcol;
  u16* lwa = As + wave * 512;
  u16* lwb = Bs + wave * 512;
  int slotx = (quad ^ ((l16 >> 1) & 3)) * 8;

  f32x4 acc[4][4] = {};

  for (int k0 = 0; k0 < K; k0 += 64) {
    __syncthreads();
    gld16(ga + k0, lwa);
    gld16(ga + (size_t)64 * K + k0, lwa + 2048);
    gld16(ga + k0 + 32, lwa + 4096);
    gld16(ga + (size_t)64 * K + k0 + 32, lwa + 6144);
    gld16(gb + k0, lwb);
    gld16(gb + (size_t)64 * K + k0, lwb + 2048);
    gld16(gb + k0 + 32, lwb + 4096);
    gld16(gb + (size_t)64 * K + k0 + 32, lwb + 6144);
    __syncthreads();
#pragma unroll
    for (int kh = 0; kh < 2; ++kh) {
      int kbase = kh * 4096;
      bf16x8 af[4], bfv[4];
#pragma unroll
      for (int i = 0; i < 4; ++i) {
        af[i] = *(const bf16x8*)&As[kbase + (wm + i * 16 + l16) * 32 + slotx];
        bfv[i] = *(const bf16x8*)&Bs[kbase + (wn + i * 16 + l16) * 32 + slotx];
      }
#pragma unroll
      for (int tm = 0; tm < 4; ++tm)
#pragma unroll
        for (int tn = 0; tn < 4; ++tn)
          acc[tm][tn] = __builtin_amdgcn_mfma_f32_16x16x32_bf16(af[tm], bfv[tn], acc[tm][tn], 0, 0, 0);
    }
  }

#pragma unroll
  for (int tm = 0; tm < 4; ++tm) {
    int row = m0 + wm + tm * 16 + quad * 4;
#pragma unroll
    for (int tn = 0; tn < 4; ++tn) {
      int col = n0 + wn + tn * 16 + l16;
      float bv = bias[col];
      if (vt) {
        u16 o4[4] __attribute__((aligned(8)));
#pragma unroll
        for (int r = 0; r < 4; ++r) o4[r] = f2bf(acc[tm][tn][r] + bv);
        int bq_ = row >> 11, s = row & 2047;
        *(uint2*)((u16*)Cv + ((size_t)(bq_ * 1024 + col)) * 2048 + s) = *(const uint2*)o4;
      } else {
#pragma unroll
        for (int r = 0; r < 4; ++r) {
          float val = acc[tm][tn][r] + bv;
          if (f32o) ((float*)Cv)[(size_t)(row + r) * N + col] = val;
          else ((u16*)Cv)[(size_t)(row + r) * N + col] = f2bf(val);
        }
      }
    }
  }
}

__global__ __launch_bounds__(256, 4) void attn_kernel(
    const u16* __restrict__ Q, const u16* __restrict__ Kg,
    const u16* __restrict__ Vtg, const u16* __restrict__ Rg,
    const float* __restrict__ pf,
    u16* __restrict__ O) {
  __shared__ __align__(16) u16 KP[64 * 72];
  __shared__ __align__(16) u16 RVs[4096];
  __shared__ __align__(16) u16 Bb[128 * 66];

  int tid = threadIdx.x, wave = tid >> 6, lane = tid & 63;
  int quad = lane >> 4, l16 = lane & 15;
  int id = blockIdx.x;
  int bh = (id & 7) + ((id >> 8) << 3);
  int s0 = ((id >> 3) & 31) * 64;
  int b = bh >> 4, h = bh & 15;
  const float* pu = pf + 5 * 1024 + h * PD;
  const float* pv = pf + 6 * 1024 + h * PD;

  int arow = wave * 16 + l16;
  int sl_base = wave * 16 + quad * 4;
  int srow = wave * 16 + (lane >> 2);
  int scol = ((lane & 3) ^ ((lane >> 3) & 3)) * 8;
  u16* kbase = KP + wave * 512;
  u16* rvbase = RVs + wave * 512;
  int kb0 = l16 * 32 + (quad ^ ((l16 >> 1) & 3)) * 8;

  const float QS = 0.18033688011112042f;
  bf16x8 qu0, qu1, qv0a, qv1a, qv0b, qv1b;
  {
    const u16* qp = Q + ((size_t)(b * SEQ + s0 + arow)) * DM + h * PD;
    int row2 = s0 + arow + 1;
    if (row2 > SEQ - 1) row2 = SEQ - 1;
    const u16* qp2 = Q + ((size_t)(b * SEQ + row2)) * DM + h * PD;
    u16 qa[16] __attribute__((aligned(16)));
    u16 qb[16] __attribute__((aligned(16)));
    *(uint4*)&qa[0] = *(const uint4*)(qp + quad * 8);
    *(uint4*)&qa[8] = *(const uint4*)(qp + 32 + quad * 8);
    *(uint4*)&qb[0] = *(const uint4*)(qp2 + quad * 8);
    *(uint4*)&qb[8] = *(const uint4*)(qp2 + 32 + quad * 8);
    u16 fu[16] __attribute__((aligned(16)));
    u16 fv0[16] __attribute__((aligned(16)));
    u16 fv1[16] __attribute__((aligned(16)));
#pragma unroll
    for (int j = 0; j < 8; ++j) {
      float u0 = pu[quad * 8 + j], u1 = pu[32 + quad * 8 + j];
      float v0 = pv[quad * 8 + j], v1 = pv[32 + quad * 8 + j];
      fu[j] = f2bf((bf2f(qa[j]) + u0) * QS);
      fu[8 + j] = f2bf((bf2f(qa[8 + j]) + u1) * QS);
      fv0[j] = f2bf((bf2f(qa[j]) + v0) * QS);
      fv0[8 + j] = f2bf((bf2f(qa[8 + j]) + v1) * QS);
      fv1[j] = f2bf((bf2f(qb[j]) + v0) * QS);
      fv1[8 + j] = f2bf((bf2f(qb[8 + j]) + v1) * QS);
    }
    __builtin_memcpy(&qu0, &fu[0], 16);
    __builtin_memcpy(&qu1, &fu[8], 16);
    __builtin_memcpy(&qv0a, &fv0[0], 16);
    __builtin_memcpy(&qv1a, &fv0[8], 16);
    __builtin_memcpy(&qv0b, &fv1[0], 16);
    __builtin_memcpy(&qv1b, &fv1[8], 16);
  }

  bf16x8 onesf;
  {
    u16 onearr[8] __attribute__((aligned(16)));
#pragma unroll
    for (int j = 0; j < 8; ++j) onearr[j] = 0x3F80;
    __builtin_memcpy(&onesf, onearr, 16);
  }

  auto dmaR = [&](int tb0) {
    int tg = tb0 + srow;
    tg = tg < 0 ? 0 : (tg > SEQ - 1 ? SEQ - 1 : tg);
    const u16* gr = Rg + (size_t)tg * DM + h * PD + scol;
    gld16(gr, rvbase);
    gld16(gr + 32, rvbase + 2048);
  };
  auto slice = [&](bf16x8 fa0, bf16x8 fa1, int slotBase, int rowOff, int lo, int hi) {
#pragma unroll
    for (int tt = 0; tt < 4; ++tt) {
      f32x4 pacc = {};
      bf16x8 b0 = *(const bf16x8*)&RVs[kb0 + tt * 512];
      bf16x8 b1 = *(const bf16x8*)&RVs[kb0 + tt * 512 + 2048];
      pacc = __builtin_amdgcn_mfma_f32_16x16x32_bf16(fa0, b0, pacc, 0, 0, 0);
      pacc = __builtin_amdgcn_mfma_f32_16x16x32_bf16(fa1, b1, pacc, 0, 0, 0);
      int rloc = tt * 16 + l16;
      bool ok = (rloc >= lo) & (rloc <= hi);
      u32 w0 = ok ? pack2(pacc[0], pacc[1]) : 0u;
      u32 w1 = ok ? pack2(pacc[2], pacc[3]) : 0u;
      int prow = (slotBase + rloc + rowOff) & 127;
      *(u32*)&Bb[prow * 66 + sl_base] = w0;
      *(u32*)&Bb[prow * 66 + sl_base + 2] = w1;
    }
  };

  f32x4 lacc = {};
  f32x4 oacc[4] = {};

  dmaR(SEQ - 65 - s0);
  __syncthreads();
  slice(qv0a, qv1a, 0, 0, 0, 63);

  for (int j0 = 0; j0 < SEQ; j0 += 64) {
    int a1 = (j0 >> 6) + 1;
    int slot = (a1 & 1) << 6;
    bool p0n = (j0 <= s0);
    bool p1n = (j0 >= s0);
    __syncthreads();
    {
      const u16* gk = Kg + (size_t)(b * SEQ + j0 + srow) * DM + h * PD + scol;
      gld16(gk, kbase);
      gld16(gk + 32, kbase + 2048);
    }
    dmaR((p0n ? (SEQ - 65 - s0) : (-65 - s0)) + 64 * a1);
    __syncthreads();

    f32x4 acc[4];
#pragma unroll
    for (int tn = 0; tn < 4; ++tn) {
      f32x4 a = {};
      bf16x8 b0 = *(const bf16x8*)&KP[kb0 + tn * 512];
      bf16x8 b1 = *(const bf16x8*)&KP[kb0 + tn * 512 + 2048];
      a = __builtin_amdgcn_mfma_f32_16x16x32_bf16(qu0, b0, a, 0, 0, 0);
      a = __builtin_amdgcn_mfma_f32_16x16x32_bf16(qu1, b1, a, 0, 0, 0);
      acc[tn] = a;
    }

    if (p0n) slice(qv0a, qv1a, slot, 0, 0, s0 + 64 - 64 * a1);
    if (p0n && p1n) {
      __syncthreads();
      dmaR(64 * a1 - s0 - 65);
      __syncthreads();
    }
    if (p1n) slice(qv0b, qv1b, slot, 1, s0 + 65 - 64 * a1, 63);
    __syncthreads();

    {
      const u16* gv = Vtg + ((size_t)(b * NH + h) * PD + srow) * SEQ + j0 + scol;
      gld16(gv, rvbase);
      gld16(gv + 32, rvbase + 2048);
    }

    int g0 = l16 - sl_base + 64 + j0;
#pragma unroll
    for (int tn = 0; tn < 4; ++tn) {
#pragma unroll
      for (int r = 0; r < 4; ++r) {
        int rl = (g0 + tn * 16 - r) & 127;
        acc[tn][r] += bf2f(Bb[rl * 66 + sl_base + r]);
      }
    }

#pragma unroll
    for (int r = 0; r < 4; ++r) {
      u32 w0 = pack2(EXP2(acc[0][r]), EXP2(acc[1][r]));
      u32 w1 = pack2(EXP2(acc[2][r]), EXP2(acc[3][r]));
      u16 ec[4] = {(u16)w0, (u16)(w0 >> 16), (u16)w1, (u16)(w1 >> 16)};
      int row = sl_base + r;
      u16* prow_ = KP + row * 72 + l16;
#pragma unroll
      for (int cr = 0; cr < 4; ++cr) {
        int c = (cr + quad) & 3;
        prow_[c * 16] = ec[c];
      }
    }
    __syncthreads();

    {
      bf16x8 pa0 = *(const bf16x8*)&KP[arow * 72 + quad * 8];
      bf16x8 pa1 = *(const bf16x8*)&KP[arow * 72 + 32 + quad * 8];
      lacc = __builtin_amdgcn_mfma_f32_16x16x32_bf16(pa0, onesf, lacc, 0, 0, 0);
      lacc = __builtin_amdgcn_mfma_f32_16x16x32_bf16(pa1, onesf, lacc, 0, 0, 0);
#pragma unroll
      for (int tp = 0; tp < 4; ++tp) {
        bf16x8 b0 = *(const bf16x8*)&RVs[kb0 + tp * 512];
        bf16x8 b1 = *(const bf16x8*)&RVs[kb0 + tp * 512 + 2048];
        oacc[tp] = __builtin_amdgcn_mfma_f32_16x16x32_bf16(pa0, b0, oacc[tp], 0, 0, 0);
        oacc[tp] = __builtin_amdgcn_mfma_f32_16x16x32_bf16(pa1, b1, oacc[tp], 0, 0, 0);
      }
    }
  }

  float li[4];
#pragma unroll
  for (int r = 0; r < 4; ++r) li[r] = 1.f / lacc[r];
#pragma unroll
  for (int tp = 0; tp < 4; ++tp) {
    int pcol = tp * 16 + l16;
#pragma unroll
    for (int r = 0; r < 4; ++r) {
      int sg = s0 + sl_base + r;
      O[((size_t)(b * SEQ + sg)) * DM + h * PD + pcol] = f2bf(oacc[tp][r] * li[r]);
    }
  }
}

extern "C" void kernel_launch(void* const* d_in, const int* in_sizes, int n_in,
                              void* d_out, int out_size, void* d_ws, size_t ws_size,
                              hipStream_t stream) {
  (void)in_sizes; (void)n_in; (void)out_size; (void)ws_size;
  const void* x  = d_in[0];
  const void* Wq = d_in[1];
  const void* bq = d_in[2];
  const void* Wk = d_in[3];
  const void* bk = d_in[4];
  const void* Wv = d_in[5];
  const void* bv = d_in[6];
  const void* Wp = d_in[7];
  const void* bp = d_in[8];
  const void* Wo = d_in[9];
  const void* bo = d_in[10];
  const void* u  = d_in[11];
  const void* v  = d_in[12];

  char* base = (char*)d_ws;
  int* flag = (int*)base;
  int* cnt1 = (int*)(base + 16);
  int* cnt2 = (int*)(base + 20);
  float* pf = (float*)(base + 64);                       // 7168 floats
  u16* wbase = (u16*)(base + 64 + 7168 * 4);
  u16* WT   = wbase;                                     // 5M elems
  u16* xb   = WT + (size_t)5 * DM * DM;                  // 4M (aliased: attn out)
  u16* sinb = xb + (size_t)2 * SEQ * DM;                 // 2M
  u16* Qb   = sinb + (size_t)SEQ * DM;                   // 4M
  u16* Kb   = Qb + (size_t)2 * SEQ * DM;                 // 4M
  u16* Vtb  = Kb + (size_t)2 * SEQ * DM;                 // 4M (Vt direct from gemm)
  u16* Rb   = Vtb + (size_t)2 * SEQ * DM;                // 2M
  u16* Ab   = xb;   // x consumed by qkv phase before attention writes here
  u16* WT4  = WT + (size_t)4 * DM * DM;

  PrepArgs pa;
  pa.x = x;
  pa.w0 = Wq; pa.w1 = Wk; pa.w2 = Wv; pa.w3 = Wp; pa.w4 = Wo;
  pa.p0 = bq; pa.p1 = bk; pa.p2 = bv; pa.p3 = bp; pa.p4 = bo; pa.p5 = u; pa.p6 = v;

  // co-residency check for the manual grid barriers (guaranteed by launch_bounds,
  // verified here; fall back to the proven 4-launch path if it ever fails)
  int occ1 = 0, occ2 = 0;
  hipOccupancyMaxActiveBlocksPerMultiprocessor(&occ1, (const void*)prep_qkv_kernel, 256, 0);
  hipOccupancyMaxActiveBlocksPerMultiprocessor(&occ2, (const void*)attn_fo_kernel, 256, 0);

  if (occ1 >= 3 && occ2 >= 4) {
    hipMemsetAsync(cnt1, 0, 8, stream);  // clears cnt1 + cnt2
    prep_qkv_kernel<<<768, 256, 0, stream>>>(pa, xb, sinb, WT, pf, flag, cnt1,
                                             Qb, Kb, Vtb, Rb);
    attn_fo_kernel<<<1024, 256, 0, stream>>>(Qb, Kb, Vtb, Rb, pf, Ab, WT4,
                                             flag, cnt2, d_out);
    return;
  }

  // fallback: proven 4-launch path
  prep_kernel<<<7452, 256, 0, stream>>>(pa, xb, sinb, WT, pf, flag);
  qkv_kernel<<<dim3(16, 48), 256, 0, stream>>>(xb, sinb, WT, pf, Qb, Kb, Vtb, Rb);
  attn_kernel<<<dim3(1024), 256, 0, stream>>>(Qb, Kb, Vtb, Rb, pf, Ab);

  GemmArgs fo;
  fo.A = Ab; fo.A3 = Ab;
  fo.Bt0 = WT4; fo.Bt1 = fo.Bt0; fo.Bt2 = fo.Bt0; fo.Bt3 = fo.Bt0;
  fo.b0 = pf + 4096; fo.b1 = fo.b0; fo.b2 = fo.b0; fo.b3 = fo.b0;
  fo.C0 = d_out; fo.C1 = d_out; fo.C2 = d_out; fo.C3 = d_out;
  fo.N = DM; fo.K = DM; fo.M3 = 0; fo.flag = flag; fo.outFp32 = 1; fo.vtrans = 0;
  gemm_bt_kernel<<<dim3(8, 32, 1), 256, 0, stream>>>(fo);
}